// Round 10
// baseline (315.459 us; speedup 1.0000x reference)
//
#include <hip/hip_runtime.h>
#include <stdint.h>

// MixMamba forward, MI355X. Round 20: tail GEMM re-tiling to 32x192 blocks
// (M-tile 32, N-tile 192, acc[6]/wave) — A-panel HBM re-reads cut 12->4 (xz),
// 3->1/6->2 (dual), 3->1 (pw2); 6 MFMA per 2-barrier K-step (was 4).
// scan9 (verified 104 µs floor), convdbl, lngm-staged, gate384, accgate,
// gludwbn, gemm_pw2 BN fusion, bnsum fold all per R9-verified state.
// B=8, L=1024 (32x32), MAMBA_DIM=192, D_INNER=384, D_STATE=16, D_CONV=4,
// DT_RANK=12, NDIR=4, RED=48, INNER_C=192, K_C=8.

#define DEV __device__ __forceinline__

typedef __attribute__((ext_vector_type(8))) short short8;
typedef __attribute__((ext_vector_type(4))) short short4v;
typedef __attribute__((ext_vector_type(4))) float f32x4;

DEV float bf(ushort v) { union { uint32_t u; float f; } c; c.u = ((uint32_t)v) << 16; return c.f; }
DEV ushort fbf(float f) {
  union { float f; uint32_t u; } c; c.f = f;
  uint32_t u = c.u;
  return (ushort)((u + 0x7FFFu + ((u >> 16) & 1u)) >> 16);  // RNE
}

#if __has_builtin(__builtin_amdgcn_exp2f)
DEV float fexp2(float x) { return __builtin_amdgcn_exp2f(x); }  // raw v_exp_f32
#else
DEV float fexp2(float x) { return __expf(x * 0.6931471805599453f); }
#endif

// lane-row (16) rotation add via DPP: x + ror<K>(x); pure VALU, no DS traffic
template<int CTRL>
DEV float rradd(float x) {
  return x + __int_as_float(__builtin_amdgcn_update_dpp(
      0, __float_as_int(x), CTRL, 0xF, 0xF, true));
}

// dir-space index j -> original L index (involution)
DEV int pmap(int i, int j) {
  if (i == 0) return j;
  if (i == 1) return 1023 - j;
  if (i == 2) return ((j & 31) << 5) | (j >> 5);
  int k = 1023 - j; return ((k & 31) << 5) | (k >> 5);
}

DEV void cvt4(const float* __restrict__ s, ushort* __restrict__ d, int blk, int tid) {
  const int idx = (blk * 256 + tid) * 4;
  float4 v = *(const float4*)(s + idx);
  d[idx] = fbf(v.x); d[idx + 1] = fbf(v.y); d[idx + 2] = fbf(v.z); d[idx + 3] = fbf(v.w);
}

// ---------------- all input conversions + xproj pad in ONE launch (3652 blocks)
__global__ __launch_bounds__(256) void prep_all(
    const float* __restrict__ x, ushort* __restrict__ xb,
    const float* __restrict__ ipw, ushort* __restrict__ ipwb,
    const float* __restrict__ opw, ushort* __restrict__ opwb,
    const float* __restrict__ pw1w, ushort* __restrict__ pw1wb,
    const float* __restrict__ pw2w, ushort* __restrict__ pw2wb,
    const float* __restrict__ xw, ushort* __restrict__ xwp)
{
  const int bx = blockIdx.x, tid = threadIdx.x;
  if (bx < 3072)      cvt4(x, xb, bx, tid);                 // 3145728
  else if (bx < 3216) cvt4(ipw, ipwb, bx - 3072, tid);      // 147456
  else if (bx < 3288) cvt4(opw, opwb, bx - 3216, tid);      // 73728
  else if (bx < 3360) cvt4(pw1w, pw1wb, bx - 3288, tid);    // 73728
  else if (bx < 3396) cvt4(pw2w, pw2wb, bx - 3360, tid);    // 36864
  else {                                                    // pad xproj (4,44,384)->(4,64,384)
    const int row = bx - 3396;             // i*64+n
    const int i = row >> 6, nn = row & 63;
    for (int c = tid; c < 384; c += 256)
      xwp[(size_t)row * 384 + c] = (nn < 44) ? fbf(xw[((size_t)i * 44 + nn) * 384 + c]) : (ushort)0;
  }
}

// ---------------- wide-N GEMM: 32x192 tile, 4 waves (2 row-halves x 2 nt-groups)
// C[M x N] = A[M x K] * Bw[N x K]^T (+bias). Grid (M/32, N/192).
template<bool BF16OUT, bool BIAS>
__global__ __launch_bounds__(256) void gemm_w192(
    const ushort* __restrict__ A, int lda,
    const ushort* __restrict__ Bw,
    const float* __restrict__ bias,
    void* __restrict__ C, int ldc, int K)
{
  __shared__ ushort As[32][40];
  __shared__ ushort Bs[192][40];
  const int tid = threadIdx.x;
  const int m0 = blockIdx.x * 32, n0 = blockIdx.y * 192;
  const int w = tid >> 6, lane = tid & 63, l15 = lane & 15, quad = lane >> 4;
  const int mrow = (w & 1) * 16, ntb = (w >> 1) * 6;
  const int brow = tid >> 2, bcol = (tid & 3) * 8;
  f32x4 acc[6] = {};
  for (int k0 = 0; k0 < K; k0 += 32) {
    __syncthreads();
    if (tid < 128)
      *(short8*)&As[brow][bcol] = *(const short8*)(A + (size_t)(m0 + brow) * lda + k0 + bcol);
#pragma unroll
    for (int rr = 0; rr < 3; rr++)
      *(short8*)&Bs[brow + rr * 64][bcol] =
          *(const short8*)(Bw + (size_t)(n0 + brow + rr * 64) * K + k0 + bcol);
    __syncthreads();
    short8 av = *(short8*)&As[mrow + l15][quad * 8];
#pragma unroll
    for (int j = 0; j < 6; j++) {
      short8 bv = *(short8*)&Bs[(ntb + j) * 16 + l15][quad * 8];
      acc[j] = __builtin_amdgcn_mfma_f32_16x16x32_bf16(av, bv, acc[j], 0, 0, 0);
    }
  }
  float* cf = (float*)C;
  ushort* cb = (ushort*)C;
#pragma unroll
  for (int j = 0; j < 6; j++) {
    const int col = n0 + (ntb + j) * 16 + l15;
    const float bv = BIAS ? bias[col] : 0.f;
#pragma unroll
    for (int r = 0; r < 4; r++) {
      const int row = m0 + mrow + quad * 4 + r;
      float v = acc[j][r] + bv;
      if (BF16OUT) cb[(size_t)row * ldc + col] = fbf(v);
      else         cf[(size_t)row * ldc + col] = v;
    }
  }
}

// ---------------- dual-config 32x192 GEMM: y==0 -> cfg0 (N=192), y in {1,2} ->
// cfg1 (N=384, two 192-tiles). Block (0,0) zeroes bnsum.
__global__ __launch_bounds__(256) void gemm_dual192(
    const ushort* __restrict__ A0, int lda0, const ushort* __restrict__ B0,
    void* __restrict__ C0, int ldc0, int K0, int bf0,
    const ushort* __restrict__ A1, int lda1, const ushort* __restrict__ B1,
    const float* __restrict__ bias1,
    void* __restrict__ C1, int ldc1, int K1, int bf1, float* __restrict__ bnsum)
{
  __shared__ ushort As[32][40];
  __shared__ ushort Bs[192][40];
  if (blockIdx.x == 0 && blockIdx.y == 0) {
    for (int k = threadIdx.x; k < 384; k += 256) bnsum[k] = 0.f;
  }
  const ushort* A; const ushort* Bw; const float* bias; void* C;
  int lda, ldc, K, bf16o, n0;
  if (blockIdx.y == 0) {
    A = A0; lda = lda0; Bw = B0; bias = nullptr; C = C0; ldc = ldc0; K = K0;
    bf16o = bf0; n0 = 0;
  } else {
    A = A1; lda = lda1; Bw = B1; bias = bias1; C = C1; ldc = ldc1; K = K1;
    bf16o = bf1; n0 = (blockIdx.y - 1) * 192;
  }
  const int tid = threadIdx.x;
  const int m0 = blockIdx.x * 32;
  const int w = tid >> 6, lane = tid & 63, l15 = lane & 15, quad = lane >> 4;
  const int mrow = (w & 1) * 16, ntb = (w >> 1) * 6;
  const int brow = tid >> 2, bcol = (tid & 3) * 8;
  f32x4 acc[6] = {};
  for (int k0 = 0; k0 < K; k0 += 32) {
    __syncthreads();
    if (tid < 128)
      *(short8*)&As[brow][bcol] = *(const short8*)(A + (size_t)(m0 + brow) * lda + k0 + bcol);
#pragma unroll
    for (int rr = 0; rr < 3; rr++)
      *(short8*)&Bs[brow + rr * 64][bcol] =
          *(const short8*)(Bw + (size_t)(n0 + brow + rr * 64) * K + k0 + bcol);
    __syncthreads();
    short8 av = *(short8*)&As[mrow + l15][quad * 8];
#pragma unroll
    for (int j = 0; j < 6; j++) {
      short8 bv = *(short8*)&Bs[(ntb + j) * 16 + l15][quad * 8];
      acc[j] = __builtin_amdgcn_mfma_f32_16x16x32_bf16(av, bv, acc[j], 0, 0, 0);
    }
  }
#pragma unroll
  for (int j = 0; j < 6; j++) {
    const int col = n0 + (ntb + j) * 16 + l15;
    const float bv = bias ? bias[col] : 0.f;
#pragma unroll
    for (int r = 0; r < 4; r++) {
      const int row = m0 + mrow + quad * 4 + r;
      float v = acc[j][r] + bv;
      if (bf16o) ((ushort*)C)[(size_t)row * ldc + col] = fbf(v);
      else       ((float*)C)[(size_t)row * ldc + col] = v;
    }
  }
}

// ---------------- pw2 GEMM (32x192 tile) with fused BN-normalize + silu on A.
// Grid (256, 1). C -> out[:, 192:384].
__global__ __launch_bounds__(256) void gemm_pw2(
    const float* __restrict__ h2, const float* __restrict__ bnsum,
    const float* __restrict__ bng, const float* __restrict__ bnb,
    const ushort* __restrict__ Bw, const float* __restrict__ bias,
    float* __restrict__ C)
{
  __shared__ ushort As[32][40];
  __shared__ ushort Bs[192][40];
  __shared__ float bsc[192], bsh[192];
  const int tid = threadIdx.x;
  const int m0 = blockIdx.x * 32;
  const int w = tid >> 6, lane = tid & 63, l15 = lane & 15, quad = lane >> 4;
  const int mrow = (w & 1) * 16, ntb = (w >> 1) * 6;
  const int brow = tid >> 2, bcol = (tid & 3) * 8;
  if (tid < 192) {
    float m = bnsum[tid] * (1.f / 8192.f);
    float va = bnsum[192 + tid] * (1.f / 8192.f) - m * m;
    float s = bng[tid] * rsqrtf(va + 1e-5f);
    bsc[tid] = s; bsh[tid] = bnb[tid] - m * s;
  }
  f32x4 acc[6] = {};
  for (int k0 = 0; k0 < 192; k0 += 32) {
    __syncthreads();           // also makes bsc/bsh visible on first pass
    if (tid < 128) {
      const float* hr = h2 + (size_t)(m0 + brow) * 192 + k0 + bcol;
      f32x4 a0 = *(const f32x4*)(hr);
      f32x4 a1 = *(const f32x4*)(hr + 4);
      short8 v;
#pragma unroll
      for (int k = 0; k < 8; k++) {
        const float xx = (k < 4) ? a0[k] : a1[k - 4];
        const float xn = xx * bsc[k0 + bcol + k] + bsh[k0 + bcol + k];
        v[k] = (short)fbf(xn / (1.f + __expf(-xn)));
      }
      *(short8*)&As[brow][bcol] = v;
    }
#pragma unroll
    for (int rr = 0; rr < 3; rr++)
      *(short8*)&Bs[brow + rr * 64][bcol] =
          *(const short8*)(Bw + (size_t)(brow + rr * 64) * 192 + k0 + bcol);
    __syncthreads();
    short8 av = *(short8*)&As[mrow + l15][quad * 8];
#pragma unroll
    for (int j = 0; j < 6; j++) {
      short8 bv = *(short8*)&Bs[(ntb + j) * 16 + l15][quad * 8];
      acc[j] = __builtin_amdgcn_mfma_f32_16x16x32_bf16(av, bv, acc[j], 0, 0, 0);
    }
  }
#pragma unroll
  for (int j = 0; j < 6; j++) {
    const int col = (ntb + j) * 16 + l15;
    const float bv = bias[col];
#pragma unroll
    for (int r = 0; r < 4; r++) {
      const int row = m0 + mrow + quad * 4 + r;
      C[(size_t)row * 384 + 192 + col] = acc[j][r] + bv;
    }
  }
}

// ---------------- convdbl: conv (k=4, causal, silu) + dbl GEMM fused.
__global__ __launch_bounds__(256) void convdbl_kernel(
    const ushort* __restrict__ xzb, const float* __restrict__ cw,
    const float* __restrict__ cb, const ushort* __restrict__ xwp,
    ushort* __restrict__ u, float* __restrict__ dbl)
{
  __shared__ __align__(16) ushort sxz[67][392];   // 52.5 KB; reused as As/Bs
  __shared__ float swt[384][4];
  __shared__ float scb[384];
  const int tid = threadIdx.x;
  const int i = blockIdx.y;
  const int m0 = blockIdx.x * 64;
  const int b = m0 >> 10, j0 = m0 & 1023;

  // ---- phase A staging: conv weights + 67-row xp window (pmap'd)
  for (int k = tid; k < 1536; k += 256) ((float*)swt)[k] = cw[(size_t)i * 1536 + k];
  for (int k = tid; k < 384; k += 256) scb[k] = cb[i * 384 + k];
  for (int g = tid; g < 67 * 96; g += 256) {
    const int rr = g / 96, c4 = (g % 96) * 4;
    const int jj = j0 - 3 + rr;
    short4v v = {};
    if (jj >= 0)
      v = *(const short4v*)(xzb + (size_t)((b << 10) + pmap(i, jj)) * 768 + c4);
    *(short4v*)&sxz[rr][c4] = v;
  }
  __syncthreads();
  // ---- conv compute: thread (r = tid>>2, cp = tid&3) does 96 cols of row r
  {
    const int r = tid >> 2, cp = tid & 3;
    ushort* ur = u + ((size_t)((i * 8 + b) << 10) + j0 + r) * 384 + cp * 96;
#pragma unroll 4
    for (int q = 0; q < 24; q++) {
      const int c = cp * 96 + q * 4;
      const short4v x0 = *(const short4v*)&sxz[r + 0][c];
      const short4v x1 = *(const short4v*)&sxz[r + 1][c];
      const short4v x2 = *(const short4v*)&sxz[r + 2][c];
      const short4v x3 = *(const short4v*)&sxz[r + 3][c];
      short4v o;
#pragma unroll
      for (int j = 0; j < 4; j++) {
        const f32x4 wv = *(const f32x4*)&swt[c + j][0];
        float s = bf((ushort)x0[j]) * wv[0] + bf((ushort)x1[j]) * wv[1]
                + bf((ushort)x2[j]) * wv[2] + bf((ushort)x3[j]) * wv[3] + scb[c + j];
        o[j] = (short)fbf(s / (1.f + __expf(-s)));
      }
      *(short4v*)(ur + q * 4) = o;
    }
  }
  // ---- phase B: GEMM dbl[m0..m0+63][0..63] = u @ xwp^T (K=384), LDS reused
  ushort (*As)[40] = (ushort(*)[40])&sxz[0][0];
  ushort (*Bs)[40] = (ushort(*)[40])(&sxz[0][0] + 2560);
  const ushort* Au = u + (size_t)i * 8192 * 384;
  const ushort* Bw = xwp + (size_t)i * 64 * 384;
  const int w = tid >> 6, lane = tid & 63, l15 = lane & 15, quad = lane >> 4;
  const int sr = tid >> 2, sc = (tid & 3) * 8;
  f32x4 acc[4] = {};
  for (int k0 = 0; k0 < 384; k0 += 32) {
    __syncthreads();   // first pass also fences conv's sxz reads + u writes
    *(short8*)&As[sr][sc] = *(const short8*)(Au + (size_t)(m0 + sr) * 384 + k0 + sc);
    *(short8*)&Bs[sr][sc] = *(const short8*)(Bw + (size_t)sr * 384 + k0 + sc);
    __syncthreads();
    short8 av = *(short8*)&As[w * 16 + l15][quad * 8];
#pragma unroll
    for (int nt = 0; nt < 4; nt++) {
      short8 bv = *(short8*)&Bs[nt * 16 + l15][quad * 8];
      acc[nt] = __builtin_amdgcn_mfma_f32_16x16x32_bf16(av, bv, acc[nt], 0, 0, 0);
    }
  }
  float* cf = dbl + (size_t)i * 8192 * 64;
#pragma unroll
  for (int nt = 0; nt < 4; nt++) {
    const int col = nt * 16 + l15;
#pragma unroll
    for (int r = 0; r < 4; r++) {
      const int row = m0 + w * 16 + quad * 4 + r;
      cf[(size_t)row * 64 + col] = acc[nt][r];
    }
  }
}

// ---------------- scan9: register-resident u/z/dt, 2 barriers/chunk, prefetch.
// grid (24, 8, 4), block 256 (16 ch x 16 states). 16 chunks of 64 steps.
#define NCH 16
#define CJ 64
__global__ __launch_bounds__(256, 3) void scan9_kernel(
    const ushort* __restrict__ u,     // [(i*8+b)*1024 + j][384] bf16
    const float*  __restrict__ dbl,   // [(i*8+b)*1024 + j][64]  f32 (dt12 B16 C16 pad)
    const ushort* __restrict__ xzb,   // [b*1024 + l][768] bf16 (z at +384)
    const float* __restrict__ alog, const float* __restrict__ dtw,
    const float* __restrict__ dtb, const float* __restrict__ Dpw,
    ushort* __restrict__ y)           // gated output
{
  const int dt0 = blockIdx.x * NCH;
  const int b = blockIdx.y, i = blockIdx.z;
  const int tid = threadIdx.x;
  const int ch = tid >> 4, n = tid & 15;
  const int srow = tid >> 2, role = tid & 3;

  __shared__ float sbc[CJ / 2][68];    // [jp][4n+2e+{0,1}] = B_n(2jp+e), C_n(2jp+e)
  __shared__ float sdu[CJ / 2][68];    // [jp][4ch+2e+{0,1}] = dl(2jp+e), dl*u(2jp+e)
  __shared__ float sy[CJ][20];         // p per (t, ch)
  __shared__ float sDp[NCH];

  float w48[4][12], dtbv4[4];
#pragma unroll
  for (int cc = 0; cc < 4; cc++) {
    const int chp = 4 * role + cc;
#pragma unroll
    for (int r = 0; r < 12; r++) w48[cc][r] = dtw[((size_t)i * 384 + dt0 + chp) * 12 + r];
    dtbv4[cc] = dtb[i * 384 + dt0 + chp];
  }
  const float L2E = 1.4426950408889634f;
  const float Al = -__expf(alog[((size_t)i * 384 + dt0 + ch) * 16 + n]) * L2E;
  if (tid < NCH) sDp[tid] = Dpw[i * 384 + dt0 + tid];

  // fma-mask: lane n collects step s (within q-block) iff (n>>2)==(s&3)
  const float selm[4] = { (n >> 2) == 0 ? 1.f : 0.f, (n >> 2) == 1 ? 1.f : 0.f,
                          (n >> 2) == 2 ? 1.f : 0.f, (n >> 2) == 3 ? 1.f : 0.f };

  const size_t rb = (size_t)(i * 8 + b) << 10;
  const ushort* ub = u + rb * 384 + dt0;
  const float* dblb = dbl + rb * 64;
  const ushort* zb = xzb + ((size_t)b << 10) * 768 + 384 + dt0;
  ushort* yb = y + rb * 384 + dt0;
  const float* sdup = &sdu[0][4 * ch];
  const float* sbcp = &sbc[0][4 * n];

  // ---- prefetch chunk 0 inputs into registers
  f32x4 nd0, nd1, nd2, ns0, ns1, ns2; short4v nu, nz;
  {
    const float* src = dblb + (size_t)srow * 64;
    nd0 = *(const f32x4*)(src); nd1 = *(const f32x4*)(src + 4); nd2 = *(const f32x4*)(src + 8);
    const float* seg = src + role * 12;
    ns0 = *(const f32x4*)(seg); ns1 = *(const f32x4*)(seg + 4); ns2 = *(const f32x4*)(seg + 8);
    nu = *(const short4v*)(ub + (size_t)srow * 384 + 4 * role);
    nz = *(const short4v*)(zb + (size_t)pmap(i, srow) * 768 + 4 * role);
  }

  float h = 0.f;

  for (int c = 0; c < 16; c++) {
    const int j0 = c * CJ;
    // ---- convert this chunk's u/z (registers; also used by epilogue)
    f32x4 uf, zf;
#pragma unroll
    for (int k = 0; k < 4; k++) { uf[k] = bf((ushort)nu[k]); zf[k] = bf((ushort)nz[k]); }
    // ---- (a) B/C transpose scatter from register segment (roles 1-3)
    if (role != 0) {
      float vals[12];
#pragma unroll
      for (int k = 0; k < 4; k++) { vals[k] = ns0[k]; vals[4 + k] = ns1[k]; vals[8 + k] = ns2[k]; }
#pragma unroll
      for (int k = 0; k < 12; k++) {
        const int f = role * 12 + k;
        if (f < 44) {
          const int isC = (f >= 28) ? 1 : 0;
          const int nn = isC ? (f - 28) : (f - 12);
          sbc[srow >> 1][4 * nn + 2 * (srow & 1) + isC] = vals[k];
        }
      }
    }
    // ---- (c) delta from register dt (fast softplus), store (dl, dl*u) pairs
    {
      float dtr[12];
#pragma unroll
      for (int k = 0; k < 4; k++) { dtr[k] = nd0[k]; dtr[4 + k] = nd1[k]; dtr[8 + k] = nd2[k]; }
#pragma unroll
      for (int cc = 0; cc < 4; cc++) {
        float s = dtbv4[cc];
#pragma unroll
        for (int r = 0; r < 12; r++) s += dtr[r] * w48[cc][r];
        const float dl = fmaxf(s, 0.f) + __logf(1.f + __expf(-fabsf(s)));
        float2 pr; pr.x = dl; pr.y = dl * uf[cc];
        *(float2*)&sdu[srow >> 1][4 * (4 * role + cc) + 2 * (srow & 1)] = pr;
      }
    }
    __syncthreads();   // S1: sbc + sdu ready; prev epilogue's sy reads complete
    // ---- T14 prefetch: issue chunk c+1 global loads; latency hides under (d)
    {
      const int cn = (c < 15) ? (c + 1) : 0;          // clamp: redundant reload ok
      const int rown = cn * CJ + srow;
      const float* src = dblb + (size_t)rown * 64;
      nd0 = *(const f32x4*)(src); nd1 = *(const f32x4*)(src + 4); nd2 = *(const f32x4*)(src + 8);
      const float* seg = src + role * 12;
      ns0 = *(const f32x4*)(seg); ns1 = *(const f32x4*)(seg + 4); ns2 = *(const f32x4*)(seg + 8);
      nu = *(const short4v*)(ub + (size_t)rown * 384 + 4 * role);
      nz = *(const short4v*)(zb + (size_t)pmap(i, rown) * 768 + 4 * role);
    }
    // ---- (d) serial 64 steps in 4 q-blocks of 16
#pragma unroll
    for (int q = 0; q < 4; q++) {
      f32x4 pq = {0.f, 0.f, 0.f, 0.f};
#pragma unroll
      for (int s2 = 0; s2 < 8; s2++) {
        const f32x4 duP = *(const f32x4*)(sdup + (q * 8 + s2) * 68);
        const f32x4 bcP = *(const f32x4*)(sbcp + (q * 8 + s2) * 68);
        {
          const float e = fexp2(duP[0] * Al);
          h = e * h + duP[1] * bcP[0];
          float p = h * bcP[1];
          p = rradd<0x124>(p); p = rradd<0x128>(p);          // T_{n&3}
          pq[s2 >> 1] = fmaf(selm[(2 * s2) & 3], p, pq[s2 >> 1]);
        }
        {
          const float e = fexp2(duP[2] * Al);
          h = e * h + duP[3] * bcP[2];
          float p = h * bcP[3];
          p = rradd<0x124>(p); p = rradd<0x128>(p);
          pq[s2 >> 1] = fmaf(selm[(2 * s2 + 1) & 3], p, pq[s2 >> 1]);
        }
      }
#pragma unroll
      for (int j = 0; j < 4; j++) {
        float t2 = rradd<0xB1>(pq[j]);   // quad_perm [1,0,3,2]  (xor 1)
        t2 = rradd<0x4E>(t2);            // quad_perm [2,3,0,1]  (xor 2)
        if ((n & 3) == 0) sy[(q << 4) | (j << 2) | (n >> 2)][ch] = t2;
      }
    }
    __syncthreads();   // S2: sy ready; (d) done reading sbc/sdu for next iter
    // ---- (e) epilogue: gate with silu(z), add u*Dp, coalesced 8B stores
    {
      const int lo = pmap(i, j0 + srow);
      const f32x4 y4 = *(const f32x4*)&sy[srow][role * 4];
      short4v o;
#pragma unroll
      for (int t = 0; t < 4; t++) {
        const float z = zf[t];
        const float val = (y4[t] + uf[t] * sDp[role * 4 + t]) * (z / (1.f + __expf(-z)));
        o[t] = (short)fbf(val);
      }
      *(short4v*)(yb + (size_t)lo * 384 + role * 4) = o;
    }
  }
}

// ---------------- fused LN stats + column partial means, LDS-staged slab.
__global__ __launch_bounds__(256) void lngm_kernel(const ushort* __restrict__ y,
                                                   float* __restrict__ G16)
{
  const int slab = blockIdx.x, b = blockIdx.y, i = blockIdx.z;
  const int tid = threadIdx.x;
  const int w = tid >> 6, lane = tid & 63;
  __shared__ float smu[64], srs[64];
  __shared__ ushort sy16[64][384];     // 48 KB
  const size_t base = (size_t)i * 8192 + b * 1024 + slab * 64;
  for (int rr = 0; rr < 16; rr++) {
    const int r = w * 16 + rr;
    const ushort* yr = y + (base + r) * 384;
    const short4v v4 = *(const short4v*)(yr + 4 * lane);         // elems 0..255
    const uint32_t v2 = *(const uint32_t*)(yr + 256 + 2 * lane); // elems 256..383
    *(short4v*)&sy16[r][4 * lane] = v4;
    *(uint32_t*)&sy16[r][256 + 2 * lane] = v2;
    float s = 0.f, ss = 0.f;
#pragma unroll
    for (int t = 0; t < 4; t++) { float v = bf((ushort)v4[t]); s += v; ss += v * v; }
    { float v = bf((ushort)(v2 & 0xffffu)); s += v; ss += v * v; }
    { float v = bf((ushort)(v2 >> 16));     s += v; ss += v * v; }
#pragma unroll
    for (int off = 1; off < 64; off <<= 1) { s += __shfl_xor(s, off, 64); ss += __shfl_xor(ss, off, 64); }
    if (lane == 0) {
      float m = s * (1.f / 384.f);
      float va = ss * (1.f / 384.f) - m * m;
      smu[r] = m;
      srs[r] = rsqrtf(va + 1e-5f);
    }
  }
  __syncthreads();
  if (tid < 192) {
    const int c0 = tid * 2;
    float s0 = 0.f, s1 = 0.f;
#pragma unroll 8
    for (int r = 0; r < 64; r++) {
      const uint32_t pv = *(const uint32_t*)&sy16[r][c0];
      const float rs = srs[r], mu = smu[r];
      s0 += (bf((ushort)(pv & 0xffffu)) - mu) * rs;
      s1 += (bf((ushort)(pv >> 16)) - mu) * rs;
    }
    float* g = G16 + ((size_t)(i * 8 + b) * 16 + slab) * 384 + c0;
    g[0] = s0; g[1] = s1;
  }
}

// ---------------- biattn gate, 384 threads: slab-sum 1 col/thread; gr GEMV
// split 8 lanes/row (48 MACs + 8-lane shuffle reduce); cs GEMV 1 out/thread.
__global__ __launch_bounds__(384) void gate_kernel(const float* __restrict__ G16,
    const float* __restrict__ lng, const float* __restrict__ lnb,
    const float* __restrict__ grw, const float* __restrict__ grb,
    const float* __restrict__ csw, const float* __restrict__ csb, float* __restrict__ cbuf)
{
  const int b = blockIdx.x, i = blockIdx.y;
  const int ib = i * 8 + b;
  const int t = threadIdx.x;
  __shared__ float sG[384];
  __shared__ float g48[48];
  {
    const float* g = G16 + (size_t)ib * 16 * 384 + t;
    float s = 0.f;
#pragma unroll
    for (int k = 0; k < 16; k++) s += g[k * 384];
    sG[t] = s * (1.f / 1024.f) * lng[t] + lnb[t];
  }
  __syncthreads();
  {
    const int row = t >> 3, seg = t & 7;      // 48 rows x 8 segs
    const float* wr = grw + (size_t)row * 384 + seg * 48;
    const float* gr = sG + seg * 48;
    float s = 0.f;
#pragma unroll
    for (int k = 0; k < 48; k++) s += gr[k] * wr[k];
    s += __shfl_xor(s, 1, 64); s += __shfl_xor(s, 2, 64); s += __shfl_xor(s, 4, 64);
    if (seg == 0) {
      s += grb[row];
      g48[row] = 0.5f * s * (1.f + erff(s * 0.70710678118f));
    }
  }
  __syncthreads();
  {
    float s = csb[t];
#pragma unroll
    for (int r = 0; r < 48; r++) s += g48[r] * csw[(size_t)t * 48 + r];
    cbuf[(size_t)ib * 384 + t] = 1.f / (1.f + __expf(-s));
  }
}

// ---------------- acc = sum_i y_i * c_i (bf16 out), coalesced 8B loads
__global__ __launch_bounds__(384) void accgate_kernel(const ushort* __restrict__ y,
    const float* __restrict__ cbuf, ushort* __restrict__ accb)
{
  const int t = threadIdx.x;
  const int row = blockIdx.x * 4 + (t / 96);
  const int cg = (t % 96) * 4;
  const int b = row >> 10;
  f32x4 s = {};
#pragma unroll
  for (int i = 0; i < 4; i++) {
    const short4v v = *(const short4v*)(y + ((size_t)i * 8192 + row) * 384 + cg);
    const f32x4 cv = *(const f32x4*)(cbuf + (size_t)(i * 8 + b) * 384 + cg);
#pragma unroll
    for (int k = 0; k < 4; k++) s[k] += bf((ushort)v[k]) * cv[k];
  }
  short4v o;
#pragma unroll
  for (int k = 0; k < 4; k++) o[k] = (short)fbf(s[k]);
  *(short4v*)(accb + (size_t)row * 384 + cg) = o;
}

// ---------------- local: fused GLU + dwconv(k=8, pad 4,3) + BN partial sums
__global__ __launch_bounds__(192) void gludwbn_kernel(const ushort* __restrict__ hchb,
    const float* __restrict__ dww, const float* __restrict__ dwb,
    float* __restrict__ h2, float* __restrict__ bnsum)
{
  const int c = threadIdx.x;           // 192
  const int lt = blockIdx.x, b = blockIdx.y;   // 16 rows per block
  __shared__ float sv[23][192];
  const int l0 = lt * 16;
#pragma unroll 4
  for (int r = 0; r < 23; r++) {
    const int ls = l0 + r - 4;
    float v = 0.f;
    if (ls >= 0 && ls < 1024) {
      const size_t rr = (size_t)((b << 10) + ls) * 384;
      const float a = bf(hchb[rr + c]);
      const float g = bf(hchb[rr + 192 + c]);
      v = a / (1.f + __expf(-g));
    }
    sv[r][c] = v;
  }
  __syncthreads();
  float wk[8];
#pragma unroll
  for (int k = 0; k < 8; k++) wk[k] = dww[(c << 3) + k];
  const float bias = dwb[c];
  float sacc = 0.f, ssacc = 0.f;
  for (int q = 0; q < 16; q++) {
    float s = bias;
#pragma unroll
    for (int k = 0; k < 8; k++) s += sv[q + k][c] * wk[k];
    h2[(size_t)((b << 10) + l0 + q) * 192 + c] = s;
    sacc += s; ssacc += s * s;
  }
  atomicAdd(&bnsum[c], sacc);
  atomicAdd(&bnsum[192 + c], ssacc);
}

extern "C" void kernel_launch(void* const* d_in, const int* in_sizes, int n_in,
                              void* d_out, int out_size, void* d_ws, size_t ws_size,
                              hipStream_t stream) {
  const float* x    = (const float*)d_in[0];
  const float* ipw  = (const float*)d_in[1];
  const float* alog = (const float*)d_in[2];
  const float* cw   = (const float*)d_in[3];
  const float* cbv  = (const float*)d_in[4];
  const float* xw   = (const float*)d_in[5];
  const float* dtw  = (const float*)d_in[6];
  const float* dtb  = (const float*)d_in[7];
  const float* Dpw  = (const float*)d_in[8];
  const float* opw  = (const float*)d_in[9];
  const float* lng  = (const float*)d_in[10];
  const float* lnb  = (const float*)d_in[11];
  const float* grw  = (const float*)d_in[12];
  const float* grb  = (const float*)d_in[13];
  const float* csw  = (const float*)d_in[14];
  const float* csb  = (const float*)d_in[15];
  const float* pw1w = (const float*)d_in[16];
  const float* pw1b = (const float*)d_in[17];
  const float* dww  = (const float*)d_in[18];
  const float* dwb  = (const float*)d_in[19];
  const float* bng  = (const float*)d_in[20];
  const float* bnb  = (const float*)d_in[21];
  const float* pw2w = (const float*)d_in[22];
  const float* pw2b = (const float*)d_in[23];
  float* out = (float*)d_out;

  char* ws = (char*)d_ws;
  // workspace (bytes); peak ~85.6 MB (proven safe by rounds 7-19)
  ushort* xb    = (ushort*)(ws + 0);          // 8192*384 bf16        6291456
  ushort* xzb   = (ushort*)(ws + 6291456);    // 8192*768 bf16       12582912
  ushort* u     = (ushort*)(ws + 18874368);   // 4*8192*384 bf16     25165824
  float*  dbl   = (float*)(ws + 44040192);    // 4*8192*64 f32        8388608
  ushort* y     = (ushort*)(ws + 52428800);   // 4*8192*384 bf16     25165824
  ushort* accb  = (ushort*)(ws + 77594624);   // 8192*384 bf16        6291456
  float*  G16   = (float*)(ws + 83886080);    // 32*16*384 f32         786432
  float*  cbuf  = (float*)(ws + 84672512);    // 32*384 f32             49152
  ushort* xwp   = (ushort*)(ws + 84721664);   // 4*64*384 bf16         196608
  ushort* ipwb  = (ushort*)(ws + 84918272);   // 768*192 bf16          294912
  ushort* opwb  = (ushort*)(ws + 85213184);   // 192*384 bf16          147456
  ushort* pw1wb = (ushort*)(ws + 85360640);   // 384*192 bf16          147456
  ushort* pw2wb = (ushort*)(ws + 85508096);   // 192*192 bf16           73728
  float*  bnsum = (float*)(ws + 85581824);    // 384 f32                 1536
  // local-branch aliases in u region (u dead after scan9)
  ushort* hchb = (ushort*)(ws + 18874368);    // 8192*384 bf16        6291456
  float*  h2   = (float*)(ws + 34603008);     // 8192*192 f32         6291456

  // 1. all conversions + pad
  prep_all<<<dim3(3652), 256, 0, stream>>>(x, xb, ipw, ipwb, opw, opwb,
                                           pw1w, pw1wb, pw2w, pw2wb, xw, xwp);
  // 2. xz = mamba_in @ in_proj_w^T (bf16), M=8192 K=192 N=768 (32x192 tiles)
  gemm_w192<true, false><<<dim3(256, 4), 256, 0, stream>>>(
      xb, 384, ipwb, nullptr, xzb, 768, 192);
  // 3+4. fused conv + dbl GEMM
  convdbl_kernel<<<dim3(128, 4), 256, 0, stream>>>(xzb, cw, cbv, xwp, u, dbl);
  // 5. scan (u dead after this)
  scan9_kernel<<<dim3(24, 8, 4), 256, 0, stream>>>(u, dbl, xzb, alog, dtw, dtb, Dpw, y);
  // 6-8. biattn
  lngm_kernel<<<dim3(16, 8, 4), 256, 0, stream>>>(y, G16);
  gate_kernel<<<dim3(8, 4), 384, 0, stream>>>(G16, lng, lnb, grw, grb, csw, csb, cbuf);
  accgate_kernel<<<dim3(2048), 384, 0, stream>>>(y, cbuf, accb);
  // 9. dual GEMM (zeroes bnsum): out_proj (N192 K384, f32) + pw1 (N384 K192, bf16)
  gemm_dual192<<<dim3(256, 3), 256, 0, stream>>>(
      accb, 384, opwb, out, 384, 384, /*bf0=*/0,
      xb + 192, 384, pw1wb, pw1b, hchb, 384, 192, /*bf1=*/1, bnsum);
  // 10. local branch: GLU+dwconv+BN stats
  gludwbn_kernel<<<dim3(64, 8), 192, 0, stream>>>(hchb, dww, dwb, h2, bnsum);
  // 11. pw2 with fused BN+silu -> out[:, 192:384] (32x192 tiles)
  gemm_pw2<<<dim3(256), 256, 0, stream>>>(h2, bnsum, bng, bnb, pw2wb, pw2b, out);
}

// Round 11
// 312.359 us; speedup vs baseline: 1.0099x; 1.0099x over previous
//
#include <hip/hip_runtime.h>
#include <stdint.h>

// MixMamba forward, MI355X. Round 21: R9 config (verified best, 312.0) +
// accgate fused into the dual GEMM's A-staging. out_proj runs as a 32x192
// single-N-pass config whose A-tile is computed on the fly: A = sum_i y_i*c_i
// (4 coalesced y loads + cbuf fma in LDS staging, same fbf rounding as the
// old accgate). -1 launch, -~37MB HBM, accb buffer dead.
// B=8, L=1024 (32x32), MAMBA_DIM=192, D_INNER=384, D_STATE=16, D_CONV=4,
// DT_RANK=12, NDIR=4, RED=48, INNER_C=192, K_C=8.

#define DEV __device__ __forceinline__

typedef __attribute__((ext_vector_type(8))) short short8;
typedef __attribute__((ext_vector_type(4))) short short4v;
typedef __attribute__((ext_vector_type(4))) float f32x4;

DEV float bf(ushort v) { union { uint32_t u; float f; } c; c.u = ((uint32_t)v) << 16; return c.f; }
DEV ushort fbf(float f) {
  union { float f; uint32_t u; } c; c.f = f;
  uint32_t u = c.u;
  return (ushort)((u + 0x7FFFu + ((u >> 16) & 1u)) >> 16);  // RNE
}

#if __has_builtin(__builtin_amdgcn_exp2f)
DEV float fexp2(float x) { return __builtin_amdgcn_exp2f(x); }  // raw v_exp_f32
#else
DEV float fexp2(float x) { return __expf(x * 0.6931471805599453f); }
#endif

// lane-row (16) rotation add via DPP: x + ror<K>(x); pure VALU, no DS traffic
template<int CTRL>
DEV float rradd(float x) {
  return x + __int_as_float(__builtin_amdgcn_update_dpp(
      0, __float_as_int(x), CTRL, 0xF, 0xF, true));
}

// dir-space index j -> original L index (involution)
DEV int pmap(int i, int j) {
  if (i == 0) return j;
  if (i == 1) return 1023 - j;
  if (i == 2) return ((j & 31) << 5) | (j >> 5);
  int k = 1023 - j; return ((k & 31) << 5) | (k >> 5);
}

DEV void cvt4(const float* __restrict__ s, ushort* __restrict__ d, int blk, int tid) {
  const int idx = (blk * 256 + tid) * 4;
  float4 v = *(const float4*)(s + idx);
  d[idx] = fbf(v.x); d[idx + 1] = fbf(v.y); d[idx + 2] = fbf(v.z); d[idx + 3] = fbf(v.w);
}

// ---------------- all input conversions + xproj pad in ONE launch (3652 blocks)
__global__ __launch_bounds__(256) void prep_all(
    const float* __restrict__ x, ushort* __restrict__ xb,
    const float* __restrict__ ipw, ushort* __restrict__ ipwb,
    const float* __restrict__ opw, ushort* __restrict__ opwb,
    const float* __restrict__ pw1w, ushort* __restrict__ pw1wb,
    const float* __restrict__ pw2w, ushort* __restrict__ pw2wb,
    const float* __restrict__ xw, ushort* __restrict__ xwp)
{
  const int bx = blockIdx.x, tid = threadIdx.x;
  if (bx < 3072)      cvt4(x, xb, bx, tid);                 // 3145728
  else if (bx < 3216) cvt4(ipw, ipwb, bx - 3072, tid);      // 147456
  else if (bx < 3288) cvt4(opw, opwb, bx - 3216, tid);      // 73728
  else if (bx < 3360) cvt4(pw1w, pw1wb, bx - 3288, tid);    // 73728
  else if (bx < 3396) cvt4(pw2w, pw2wb, bx - 3360, tid);    // 36864
  else {                                                    // pad xproj (4,44,384)->(4,64,384)
    const int row = bx - 3396;             // i*64+n
    const int i = row >> 6, nn = row & 63;
    for (int c = tid; c < 384; c += 256)
      xwp[(size_t)row * 384 + c] = (nn < 44) ? fbf(xw[((size_t)i * 44 + nn) * 384 + c]) : (ushort)0;
  }
}

// ---------------- MFMA GEMM: C[M x N] = A[M x K] * Bw[N x K]^T (+bias), z-batched
template<bool BF16OUT, bool BIAS>
__global__ __launch_bounds__(256) void gemm_bt(
    const ushort* __restrict__ A, long long sAz, int lda,
    const ushort* __restrict__ Bw, long long sBz,
    const float* __restrict__ bias,
    void* __restrict__ C, long long sCz, int ldc, int coff, int K)
{
  __shared__ ushort As[64][40];
  __shared__ ushort Bs[64][40];
  A += (size_t)blockIdx.z * sAz;
  Bw += (size_t)blockIdx.z * sBz;
  const int tid = threadIdx.x;
  const int m0 = blockIdx.x * 64, n0 = blockIdx.y * 64;
  const int w = tid >> 6, lane = tid & 63, l15 = lane & 15, quad = lane >> 4;
  const int sr = tid >> 2, sc = (tid & 3) * 8;
  f32x4 acc[4] = {};
  for (int k0 = 0; k0 < K; k0 += 32) {
    __syncthreads();
    *(short8*)&As[sr][sc] = *(const short8*)(A + (size_t)(m0 + sr) * lda + k0 + sc);
    *(short8*)&Bs[sr][sc] = *(const short8*)(Bw + (size_t)(n0 + sr) * K + k0 + sc);
    __syncthreads();
    short8 av = *(short8*)&As[w * 16 + l15][quad * 8];
#pragma unroll
    for (int nt = 0; nt < 4; nt++) {
      short8 bv = *(short8*)&Bs[nt * 16 + l15][quad * 8];
      acc[nt] = __builtin_amdgcn_mfma_f32_16x16x32_bf16(av, bv, acc[nt], 0, 0, 0);
    }
  }
  float* cf = (float*)C + (size_t)blockIdx.z * sCz;
  ushort* cb = (ushort*)C + (size_t)blockIdx.z * sCz;
#pragma unroll
  for (int nt = 0; nt < 4; nt++) {
    const int col = n0 + nt * 16 + l15;
    const float bv = BIAS ? bias[col] : 0.f;
#pragma unroll
    for (int r = 0; r < 4; r++) {
      const int row = m0 + w * 16 + quad * 4 + r;
      float v = acc[nt][r] + bv;
      if (BF16OUT) cb[(size_t)row * ldc + coff + col] = fbf(v);
      else         cf[(size_t)row * ldc + coff + col] = v;
    }
  }
}

// ---------------- dual GEMM with fused accgate on the out_proj A operand.
// Grid (256, 3), 32x192 tiles, 4 waves (2 row-halves x 2 nt-groups of 6).
// y==0: out_proj — A computed on the fly: A[row][k] = sum_i y[i][row][k]*c[i][b][k]
//       (identical fbf rounding to the old accgate), B=opwb K=384, f32 -> out[:,0:192].
// y in {1,2}: pw1 — A=xb+192, B=pw1wb K=192, +bias, bf16 -> hchb (n0=(y-1)*192).
// Block (0,0) zeroes bnsum.
__global__ __launch_bounds__(256) void gemm_dualfuse(
    const ushort* __restrict__ yv, const float* __restrict__ cbuf,
    const ushort* __restrict__ B0, float* __restrict__ C0,
    const ushort* __restrict__ A1, const ushort* __restrict__ B1,
    const float* __restrict__ bias1, ushort* __restrict__ C1,
    float* __restrict__ bnsum)
{
  __shared__ ushort As[32][40];
  __shared__ ushort Bs[192][40];
  __shared__ float scb[4 * 384];
  if (blockIdx.x == 0 && blockIdx.y == 0) {
    for (int k = threadIdx.x; k < 384; k += 256) bnsum[k] = 0.f;
  }
  const int tid = threadIdx.x;
  const int m0 = blockIdx.x * 32;
  const int w = tid >> 6, lane = tid & 63, l15 = lane & 15, quad = lane >> 4;
  const int mrow = (w & 1) * 16, ntb = (w >> 1) * 6;
  const int brow = tid >> 2, bcol = (tid & 3) * 8;
  const int cfg0 = (blockIdx.y == 0);
  const int b = m0 >> 10;
  const ushort* Bw; int K, n0;
  if (cfg0) {
    Bw = B0; K = 384; n0 = 0;
    for (int k = tid; k < 1536; k += 256)
      scb[k] = cbuf[(size_t)((k / 384) * 8 + b) * 384 + (k % 384)];
  } else {
    Bw = B1; K = 192; n0 = (blockIdx.y - 1) * 192;
  }
  f32x4 acc[6] = {};
  for (int k0 = 0; k0 < K; k0 += 32) {
    __syncthreads();           // first pass also makes scb visible
    if (tid < 128) {
      const int row = m0 + brow, kc = k0 + bcol;
      if (cfg0) {
        float a8[8] = {};
#pragma unroll
        for (int i = 0; i < 4; i++) {
          const short8 v = *(const short8*)(yv + ((size_t)i * 8192 + row) * 384 + kc);
          const float* cv = &scb[i * 384 + kc];
#pragma unroll
          for (int k = 0; k < 8; k++) a8[k] += bf((ushort)v[k]) * cv[k];
        }
        short8 o;
#pragma unroll
        for (int k = 0; k < 8; k++) o[k] = (short)fbf(a8[k]);
        *(short8*)&As[brow][bcol] = o;
      } else {
        *(short8*)&As[brow][bcol] = *(const short8*)(A1 + (size_t)row * 384 + kc);
      }
    }
#pragma unroll
    for (int rr = 0; rr < 3; rr++)
      *(short8*)&Bs[brow + rr * 64][bcol] =
          *(const short8*)(Bw + (size_t)(n0 + brow + rr * 64) * K + k0 + bcol);
    __syncthreads();
    short8 av = *(short8*)&As[mrow + l15][quad * 8];
#pragma unroll
    for (int j = 0; j < 6; j++) {
      short8 bv = *(short8*)&Bs[(ntb + j) * 16 + l15][quad * 8];
      acc[j] = __builtin_amdgcn_mfma_f32_16x16x32_bf16(av, bv, acc[j], 0, 0, 0);
    }
  }
#pragma unroll
  for (int j = 0; j < 6; j++) {
    const int col = n0 + (ntb + j) * 16 + l15;
#pragma unroll
    for (int r = 0; r < 4; r++) {
      const int row = m0 + mrow + quad * 4 + r;
      if (cfg0) C0[(size_t)row * 384 + col] = acc[j][r];
      else      C1[(size_t)row * 384 + col] = fbf(acc[j][r] + bias1[col]);
    }
  }
}

// ---------------- pw2 GEMM with fused BN-normalize + silu on the A operand.
__global__ __launch_bounds__(256) void gemm_pw2(
    const float* __restrict__ h2, const float* __restrict__ bnsum,
    const float* __restrict__ bng, const float* __restrict__ bnb,
    const ushort* __restrict__ Bw, const float* __restrict__ bias,
    float* __restrict__ C)
{
  __shared__ ushort As[64][40];
  __shared__ ushort Bs[64][40];
  __shared__ float bsc[192], bsh[192];
  const int tid = threadIdx.x;
  const int m0 = blockIdx.x * 64, n0 = blockIdx.y * 64;
  const int w = tid >> 6, lane = tid & 63, l15 = lane & 15, quad = lane >> 4;
  const int sr = tid >> 2, sc = (tid & 3) * 8;
  for (int cth = tid; cth < 192; cth += 256) {
    float m = bnsum[cth] * (1.f / 8192.f);
    float va = bnsum[192 + cth] * (1.f / 8192.f) - m * m;
    float s = bng[cth] * rsqrtf(va + 1e-5f);
    bsc[cth] = s; bsh[cth] = bnb[cth] - m * s;
  }
  f32x4 acc[4] = {};
  for (int k0 = 0; k0 < 192; k0 += 32) {
    __syncthreads();           // also makes bsc/bsh visible on first pass
    {
      const float* hr = h2 + (size_t)(m0 + sr) * 192 + k0 + sc;
      f32x4 a0 = *(const f32x4*)(hr);
      f32x4 a1 = *(const f32x4*)(hr + 4);
      short8 v;
#pragma unroll
      for (int k = 0; k < 8; k++) {
        const float xx = (k < 4) ? a0[k] : a1[k - 4];
        const float xn = xx * bsc[k0 + sc + k] + bsh[k0 + sc + k];
        v[k] = (short)fbf(xn / (1.f + __expf(-xn)));
      }
      *(short8*)&As[sr][sc] = v;
    }
    *(short8*)&Bs[sr][sc] = *(const short8*)(Bw + (size_t)(n0 + sr) * 192 + k0 + sc);
    __syncthreads();
    short8 av = *(short8*)&As[w * 16 + l15][quad * 8];
#pragma unroll
    for (int nt = 0; nt < 4; nt++) {
      short8 bv = *(short8*)&Bs[nt * 16 + l15][quad * 8];
      acc[nt] = __builtin_amdgcn_mfma_f32_16x16x32_bf16(av, bv, acc[nt], 0, 0, 0);
    }
  }
#pragma unroll
  for (int nt = 0; nt < 4; nt++) {
    const int col = n0 + nt * 16 + l15;
    const float bv = bias[col];
#pragma unroll
    for (int r = 0; r < 4; r++) {
      const int row = m0 + w * 16 + quad * 4 + r;
      C[(size_t)row * 384 + 192 + col] = acc[nt][r] + bv;
    }
  }
}

// ---------------- convdbl: conv (k=4, causal, silu) + dbl GEMM fused.
__global__ __launch_bounds__(256) void convdbl_kernel(
    const ushort* __restrict__ xzb, const float* __restrict__ cw,
    const float* __restrict__ cb, const ushort* __restrict__ xwp,
    ushort* __restrict__ u, float* __restrict__ dbl)
{
  __shared__ __align__(16) ushort sxz[67][392];   // 52.5 KB; reused as As/Bs
  __shared__ float swt[384][4];
  __shared__ float scb[384];
  const int tid = threadIdx.x;
  const int i = blockIdx.y;
  const int m0 = blockIdx.x * 64;
  const int b = m0 >> 10, j0 = m0 & 1023;

  // ---- phase A staging: conv weights + 67-row xp window (pmap'd)
  for (int k = tid; k < 1536; k += 256) ((float*)swt)[k] = cw[(size_t)i * 1536 + k];
  for (int k = tid; k < 384; k += 256) scb[k] = cb[i * 384 + k];
  for (int g = tid; g < 67 * 96; g += 256) {
    const int rr = g / 96, c4 = (g % 96) * 4;
    const int jj = j0 - 3 + rr;
    short4v v = {};
    if (jj >= 0)
      v = *(const short4v*)(xzb + (size_t)((b << 10) + pmap(i, jj)) * 768 + c4);
    *(short4v*)&sxz[rr][c4] = v;
  }
  __syncthreads();
  // ---- conv compute: thread (r = tid>>2, cp = tid&3) does 96 cols of row r
  {
    const int r = tid >> 2, cp = tid & 3;
    ushort* ur = u + ((size_t)((i * 8 + b) << 10) + j0 + r) * 384 + cp * 96;
#pragma unroll 4
    for (int q = 0; q < 24; q++) {
      const int c = cp * 96 + q * 4;
      const short4v x0 = *(const short4v*)&sxz[r + 0][c];
      const short4v x1 = *(const short4v*)&sxz[r + 1][c];
      const short4v x2 = *(const short4v*)&sxz[r + 2][c];
      const short4v x3 = *(const short4v*)&sxz[r + 3][c];
      short4v o;
#pragma unroll
      for (int j = 0; j < 4; j++) {
        const f32x4 wv = *(const f32x4*)&swt[c + j][0];
        float s = bf((ushort)x0[j]) * wv[0] + bf((ushort)x1[j]) * wv[1]
                + bf((ushort)x2[j]) * wv[2] + bf((ushort)x3[j]) * wv[3] + scb[c + j];
        o[j] = (short)fbf(s / (1.f + __expf(-s)));
      }
      *(short4v*)(ur + q * 4) = o;
    }
  }
  // ---- phase B: GEMM dbl[m0..m0+63][0..63] = u @ xwp^T (K=384), LDS reused
  ushort (*As)[40] = (ushort(*)[40])&sxz[0][0];
  ushort (*Bs)[40] = (ushort(*)[40])(&sxz[0][0] + 2560);
  const ushort* Au = u + (size_t)i * 8192 * 384;
  const ushort* Bw = xwp + (size_t)i * 64 * 384;
  const int w = tid >> 6, lane = tid & 63, l15 = lane & 15, quad = lane >> 4;
  const int sr = tid >> 2, sc = (tid & 3) * 8;
  f32x4 acc[4] = {};
  for (int k0 = 0; k0 < 384; k0 += 32) {
    __syncthreads();   // first pass also fences conv's sxz reads + u writes
    *(short8*)&As[sr][sc] = *(const short8*)(Au + (size_t)(m0 + sr) * 384 + k0 + sc);
    *(short8*)&Bs[sr][sc] = *(const short8*)(Bw + (size_t)sr * 384 + k0 + sc);
    __syncthreads();
    short8 av = *(short8*)&As[w * 16 + l15][quad * 8];
#pragma unroll
    for (int nt = 0; nt < 4; nt++) {
      short8 bv = *(short8*)&Bs[nt * 16 + l15][quad * 8];
      acc[nt] = __builtin_amdgcn_mfma_f32_16x16x32_bf16(av, bv, acc[nt], 0, 0, 0);
    }
  }
  float* cf = dbl + (size_t)i * 8192 * 64;
#pragma unroll
  for (int nt = 0; nt < 4; nt++) {
    const int col = nt * 16 + l15;
#pragma unroll
    for (int r = 0; r < 4; r++) {
      const int row = m0 + w * 16 + quad * 4 + r;
      cf[(size_t)row * 64 + col] = acc[nt][r];
    }
  }
}

// ---------------- scan9: register-resident u/z/dt, 2 barriers/chunk, prefetch.
// grid (24, 8, 4), block 256 (16 ch x 16 states). 16 chunks of 64 steps.
#define NCH 16
#define CJ 64
__global__ __launch_bounds__(256, 3) void scan9_kernel(
    const ushort* __restrict__ u,     // [(i*8+b)*1024 + j][384] bf16
    const float*  __restrict__ dbl,   // [(i*8+b)*1024 + j][64]  f32 (dt12 B16 C16 pad)
    const ushort* __restrict__ xzb,   // [b*1024 + l][768] bf16 (z at +384)
    const float* __restrict__ alog, const float* __restrict__ dtw,
    const float* __restrict__ dtb, const float* __restrict__ Dpw,
    ushort* __restrict__ y)           // gated output
{
  const int dt0 = blockIdx.x * NCH;
  const int b = blockIdx.y, i = blockIdx.z;
  const int tid = threadIdx.x;
  const int ch = tid >> 4, n = tid & 15;
  const int srow = tid >> 2, role = tid & 3;

  __shared__ float sbc[CJ / 2][68];    // [jp][4n+2e+{0,1}] = B_n(2jp+e), C_n(2jp+e)
  __shared__ float sdu[CJ / 2][68];    // [jp][4ch+2e+{0,1}] = dl(2jp+e), dl*u(2jp+e)
  __shared__ float sy[CJ][20];         // p per (t, ch)
  __shared__ float sDp[NCH];

  float w48[4][12], dtbv4[4];
#pragma unroll
  for (int cc = 0; cc < 4; cc++) {
    const int chp = 4 * role + cc;
#pragma unroll
    for (int r = 0; r < 12; r++) w48[cc][r] = dtw[((size_t)i * 384 + dt0 + chp) * 12 + r];
    dtbv4[cc] = dtb[i * 384 + dt0 + chp];
  }
  const float L2E = 1.4426950408889634f;
  const float Al = -__expf(alog[((size_t)i * 384 + dt0 + ch) * 16 + n]) * L2E;
  if (tid < NCH) sDp[tid] = Dpw[i * 384 + dt0 + tid];

  // fma-mask: lane n collects step s (within q-block) iff (n>>2)==(s&3)
  const float selm[4] = { (n >> 2) == 0 ? 1.f : 0.f, (n >> 2) == 1 ? 1.f : 0.f,
                          (n >> 2) == 2 ? 1.f : 0.f, (n >> 2) == 3 ? 1.f : 0.f };

  const size_t rb = (size_t)(i * 8 + b) << 10;
  const ushort* ub = u + rb * 384 + dt0;
  const float* dblb = dbl + rb * 64;
  const ushort* zb = xzb + ((size_t)b << 10) * 768 + 384 + dt0;
  ushort* yb = y + rb * 384 + dt0;
  const float* sdup = &sdu[0][4 * ch];
  const float* sbcp = &sbc[0][4 * n];

  // ---- prefetch chunk 0 inputs into registers
  f32x4 nd0, nd1, nd2, ns0, ns1, ns2; short4v nu, nz;
  {
    const float* src = dblb + (size_t)srow * 64;
    nd0 = *(const f32x4*)(src); nd1 = *(const f32x4*)(src + 4); nd2 = *(const f32x4*)(src + 8);
    const float* seg = src + role * 12;
    ns0 = *(const f32x4*)(seg); ns1 = *(const f32x4*)(seg + 4); ns2 = *(const f32x4*)(seg + 8);
    nu = *(const short4v*)(ub + (size_t)srow * 384 + 4 * role);
    nz = *(const short4v*)(zb + (size_t)pmap(i, srow) * 768 + 4 * role);
  }

  float h = 0.f;

  for (int c = 0; c < 16; c++) {
    const int j0 = c * CJ;
    // ---- convert this chunk's u/z (registers; also used by epilogue)
    f32x4 uf, zf;
#pragma unroll
    for (int k = 0; k < 4; k++) { uf[k] = bf((ushort)nu[k]); zf[k] = bf((ushort)nz[k]); }
    // ---- (a) B/C transpose scatter from register segment (roles 1-3)
    if (role != 0) {
      float vals[12];
#pragma unroll
      for (int k = 0; k < 4; k++) { vals[k] = ns0[k]; vals[4 + k] = ns1[k]; vals[8 + k] = ns2[k]; }
#pragma unroll
      for (int k = 0; k < 12; k++) {
        const int f = role * 12 + k;
        if (f < 44) {
          const int isC = (f >= 28) ? 1 : 0;
          const int nn = isC ? (f - 28) : (f - 12);
          sbc[srow >> 1][4 * nn + 2 * (srow & 1) + isC] = vals[k];
        }
      }
    }
    // ---- (c) delta from register dt (fast softplus), store (dl, dl*u) pairs
    {
      float dtr[12];
#pragma unroll
      for (int k = 0; k < 4; k++) { dtr[k] = nd0[k]; dtr[4 + k] = nd1[k]; dtr[8 + k] = nd2[k]; }
#pragma unroll
      for (int cc = 0; cc < 4; cc++) {
        float s = dtbv4[cc];
#pragma unroll
        for (int r = 0; r < 12; r++) s += dtr[r] * w48[cc][r];
        const float dl = fmaxf(s, 0.f) + __logf(1.f + __expf(-fabsf(s)));
        float2 pr; pr.x = dl; pr.y = dl * uf[cc];
        *(float2*)&sdu[srow >> 1][4 * (4 * role + cc) + 2 * (srow & 1)] = pr;
      }
    }
    __syncthreads();   // S1: sbc + sdu ready; prev epilogue's sy reads complete
    // ---- T14 prefetch: issue chunk c+1 global loads; latency hides under (d)
    {
      const int cn = (c < 15) ? (c + 1) : 0;          // clamp: redundant reload ok
      const int rown = cn * CJ + srow;
      const float* src = dblb + (size_t)rown * 64;
      nd0 = *(const f32x4*)(src); nd1 = *(const f32x4*)(src + 4); nd2 = *(const f32x4*)(src + 8);
      const float* seg = src + role * 12;
      ns0 = *(const f32x4*)(seg); ns1 = *(const f32x4*)(seg + 4); ns2 = *(const f32x4*)(seg + 8);
      nu = *(const short4v*)(ub + (size_t)rown * 384 + 4 * role);
      nz = *(const short4v*)(zb + (size_t)pmap(i, rown) * 768 + 4 * role);
    }
    // ---- (d) serial 64 steps in 4 q-blocks of 16
#pragma unroll
    for (int q = 0; q < 4; q++) {
      f32x4 pq = {0.f, 0.f, 0.f, 0.f};
#pragma unroll
      for (int s2 = 0; s2 < 8; s2++) {
        const f32x4 duP = *(const f32x4*)(sdup + (q * 8 + s2) * 68);
        const f32x4 bcP = *(const f32x4*)(sbcp + (q * 8 + s2) * 68);
        {
          const float e = fexp2(duP[0] * Al);
          h = e * h + duP[1] * bcP[0];
          float p = h * bcP[1];
          p = rradd<0x124>(p); p = rradd<0x128>(p);          // T_{n&3}
          pq[s2 >> 1] = fmaf(selm[(2 * s2) & 3], p, pq[s2 >> 1]);
        }
        {
          const float e = fexp2(duP[2] * Al);
          h = e * h + duP[3] * bcP[2];
          float p = h * bcP[3];
          p = rradd<0x124>(p); p = rradd<0x128>(p);
          pq[s2 >> 1] = fmaf(selm[(2 * s2 + 1) & 3], p, pq[s2 >> 1]);
        }
      }
#pragma unroll
      for (int j = 0; j < 4; j++) {
        float t2 = rradd<0xB1>(pq[j]);   // quad_perm [1,0,3,2]  (xor 1)
        t2 = rradd<0x4E>(t2);            // quad_perm [2,3,0,1]  (xor 2)
        if ((n & 3) == 0) sy[(q << 4) | (j << 2) | (n >> 2)][ch] = t2;
      }
    }
    __syncthreads();   // S2: sy ready; (d) done reading sbc/sdu for next iter
    // ---- (e) epilogue: gate with silu(z), add u*Dp, coalesced 8B stores
    {
      const int lo = pmap(i, j0 + srow);
      const f32x4 y4 = *(const f32x4*)&sy[srow][role * 4];
      short4v o;
#pragma unroll
      for (int t = 0; t < 4; t++) {
        const float z = zf[t];
        const float val = (y4[t] + uf[t] * sDp[role * 4 + t]) * (z / (1.f + __expf(-z)));
        o[t] = (short)fbf(val);
      }
      *(short4v*)(yb + (size_t)lo * 384 + role * 4) = o;
    }
  }
}

// ---------------- fused LN stats + column partial means, LDS-staged slab.
__global__ __launch_bounds__(256) void lngm_kernel(const ushort* __restrict__ y,
                                                   float* __restrict__ G16)
{
  const int slab = blockIdx.x, b = blockIdx.y, i = blockIdx.z;
  const int tid = threadIdx.x;
  const int w = tid >> 6, lane = tid & 63;
  __shared__ float smu[64], srs[64];
  __shared__ ushort sy16[64][384];     // 48 KB
  const size_t base = (size_t)i * 8192 + b * 1024 + slab * 64;
  for (int rr = 0; rr < 16; rr++) {
    const int r = w * 16 + rr;
    const ushort* yr = y + (base + r) * 384;
    const short4v v4 = *(const short4v*)(yr + 4 * lane);         // elems 0..255
    const uint32_t v2 = *(const uint32_t*)(yr + 256 + 2 * lane); // elems 256..383
    *(short4v*)&sy16[r][4 * lane] = v4;
    *(uint32_t*)&sy16[r][256 + 2 * lane] = v2;
    float s = 0.f, ss = 0.f;
#pragma unroll
    for (int t = 0; t < 4; t++) { float v = bf((ushort)v4[t]); s += v; ss += v * v; }
    { float v = bf((ushort)(v2 & 0xffffu)); s += v; ss += v * v; }
    { float v = bf((ushort)(v2 >> 16));     s += v; ss += v * v; }
#pragma unroll
    for (int off = 1; off < 64; off <<= 1) { s += __shfl_xor(s, off, 64); ss += __shfl_xor(ss, off, 64); }
    if (lane == 0) {
      float m = s * (1.f / 384.f);
      float va = ss * (1.f / 384.f) - m * m;
      smu[r] = m;
      srs[r] = rsqrtf(va + 1e-5f);
    }
  }
  __syncthreads();
  if (tid < 192) {
    const int c0 = tid * 2;
    float s0 = 0.f, s1 = 0.f;
#pragma unroll 8
    for (int r = 0; r < 64; r++) {
      const uint32_t pv = *(const uint32_t*)&sy16[r][c0];
      const float rs = srs[r], mu = smu[r];
      s0 += (bf((ushort)(pv & 0xffffu)) - mu) * rs;
      s1 += (bf((ushort)(pv >> 16)) - mu) * rs;
    }
    float* g = G16 + ((size_t)(i * 8 + b) * 16 + slab) * 384 + c0;
    g[0] = s0; g[1] = s1;
  }
}

// ---------------- biattn gate, 384 threads: slab-sum 1 col/thread; gr GEMV
// split 8 lanes/row (48 MACs + 8-lane shuffle reduce); cs GEMV 1 out/thread.
__global__ __launch_bounds__(384) void gate_kernel(const float* __restrict__ G16,
    const float* __restrict__ lng, const float* __restrict__ lnb,
    const float* __restrict__ grw, const float* __restrict__ grb,
    const float* __restrict__ csw, const float* __restrict__ csb, float* __restrict__ cbuf)
{
  const int b = blockIdx.x, i = blockIdx.y;
  const int ib = i * 8 + b;
  const int t = threadIdx.x;
  __shared__ float sG[384];
  __shared__ float g48[48];
  {
    const float* g = G16 + (size_t)ib * 16 * 384 + t;
    float s = 0.f;
#pragma unroll
    for (int k = 0; k < 16; k++) s += g[k * 384];
    sG[t] = s * (1.f / 1024.f) * lng[t] + lnb[t];
  }
  __syncthreads();
  {
    const int row = t >> 3, seg = t & 7;      // 48 rows x 8 segs
    const float* wr = grw + (size_t)row * 384 + seg * 48;
    const float* gr = sG + seg * 48;
    float s = 0.f;
#pragma unroll
    for (int k = 0; k < 48; k++) s += gr[k] * wr[k];
    s += __shfl_xor(s, 1, 64); s += __shfl_xor(s, 2, 64); s += __shfl_xor(s, 4, 64);
    if (seg == 0) {
      s += grb[row];
      g48[row] = 0.5f * s * (1.f + erff(s * 0.70710678118f));
    }
  }
  __syncthreads();
  {
    float s = csb[t];
#pragma unroll
    for (int r = 0; r < 48; r++) s += g48[r] * csw[(size_t)t * 48 + r];
    cbuf[(size_t)ib * 384 + t] = 1.f / (1.f + __expf(-s));
  }
}

// ---------------- local: fused GLU + dwconv(k=8, pad 4,3) + BN partial sums
__global__ __launch_bounds__(192) void gludwbn_kernel(const ushort* __restrict__ hchb,
    const float* __restrict__ dww, const float* __restrict__ dwb,
    float* __restrict__ h2, float* __restrict__ bnsum)
{
  const int c = threadIdx.x;           // 192
  const int lt = blockIdx.x, b = blockIdx.y;   // 16 rows per block
  __shared__ float sv[23][192];
  const int l0 = lt * 16;
#pragma unroll 4
  for (int r = 0; r < 23; r++) {
    const int ls = l0 + r - 4;
    float v = 0.f;
    if (ls >= 0 && ls < 1024) {
      const size_t rr = (size_t)((b << 10) + ls) * 384;
      const float a = bf(hchb[rr + c]);
      const float g = bf(hchb[rr + 192 + c]);
      v = a / (1.f + __expf(-g));
    }
    sv[r][c] = v;
  }
  __syncthreads();
  float wk[8];
#pragma unroll
  for (int k = 0; k < 8; k++) wk[k] = dww[(c << 3) + k];
  const float bias = dwb[c];
  float sacc = 0.f, ssacc = 0.f;
  for (int q = 0; q < 16; q++) {
    float s = bias;
#pragma unroll
    for (int k = 0; k < 8; k++) s += sv[q + k][c] * wk[k];
    h2[(size_t)((b << 10) + l0 + q) * 192 + c] = s;
    sacc += s; ssacc += s * s;
  }
  atomicAdd(&bnsum[c], sacc);
  atomicAdd(&bnsum[192 + c], ssacc);
}

extern "C" void kernel_launch(void* const* d_in, const int* in_sizes, int n_in,
                              void* d_out, int out_size, void* d_ws, size_t ws_size,
                              hipStream_t stream) {
  const float* x    = (const float*)d_in[0];
  const float* ipw  = (const float*)d_in[1];
  const float* alog = (const float*)d_in[2];
  const float* cw   = (const float*)d_in[3];
  const float* cbv  = (const float*)d_in[4];
  const float* xw   = (const float*)d_in[5];
  const float* dtw  = (const float*)d_in[6];
  const float* dtb  = (const float*)d_in[7];
  const float* Dpw  = (const float*)d_in[8];
  const float* opw  = (const float*)d_in[9];
  const float* lng  = (const float*)d_in[10];
  const float* lnb  = (const float*)d_in[11];
  const float* grw  = (const float*)d_in[12];
  const float* grb  = (const float*)d_in[13];
  const float* csw  = (const float*)d_in[14];
  const float* csb  = (const float*)d_in[15];
  const float* pw1w = (const float*)d_in[16];
  const float* pw1b = (const float*)d_in[17];
  const float* dww  = (const float*)d_in[18];
  const float* dwb  = (const float*)d_in[19];
  const float* bng  = (const float*)d_in[20];
  const float* bnb  = (const float*)d_in[21];
  const float* pw2w = (const float*)d_in[22];
  const float* pw2b = (const float*)d_in[23];
  float* out = (float*)d_out;

  char* ws = (char*)d_ws;
  // workspace (bytes); peak ~85.6 MB (proven safe by rounds 7-20)
  ushort* xb    = (ushort*)(ws + 0);          // 8192*384 bf16        6291456
  ushort* xzb   = (ushort*)(ws + 6291456);    // 8192*768 bf16       12582912
  ushort* u     = (ushort*)(ws + 18874368);   // 4*8192*384 bf16     25165824
  float*  dbl   = (float*)(ws + 44040192);    // 4*8192*64 f32        8388608
  ushort* y     = (ushort*)(ws + 52428800);   // 4*8192*384 bf16     25165824
  float*  G16   = (float*)(ws + 83886080);    // 32*16*384 f32         786432
  float*  cbuf  = (float*)(ws + 84672512);    // 32*384 f32             49152
  ushort* xwp   = (ushort*)(ws + 84721664);   // 4*64*384 bf16         196608
  ushort* ipwb  = (ushort*)(ws + 84918272);   // 768*192 bf16          294912
  ushort* opwb  = (ushort*)(ws + 85213184);   // 192*384 bf16          147456
  ushort* pw1wb = (ushort*)(ws + 85360640);   // 384*192 bf16          147456
  ushort* pw2wb = (ushort*)(ws + 85508096);   // 192*192 bf16           73728
  float*  bnsum = (float*)(ws + 85581824);    // 384 f32                 1536
  // local-branch aliases in u region (u dead after scan9)
  ushort* hchb = (ushort*)(ws + 18874368);    // 8192*384 bf16        6291456
  float*  h2   = (float*)(ws + 34603008);     // 8192*192 f32         6291456

  // 1. all conversions + pad
  prep_all<<<dim3(3652), 256, 0, stream>>>(x, xb, ipw, ipwb, opw, opwb,
                                           pw1w, pw1wb, pw2w, pw2wb, xw, xwp);
  // 2. xz = mamba_in @ in_proj_w^T (bf16), M=8192 K=192 N=768
  gemm_bt<true, false><<<dim3(128, 12, 1), 256, 0, stream>>>(
      xb, 0, 384, ipwb, 0, nullptr, xzb, 0, 768, 0, 192);
  // 3+4. fused conv + dbl GEMM
  convdbl_kernel<<<dim3(128, 4), 256, 0, stream>>>(xzb, cw, cbv, xwp, u, dbl);
  // 5. scan (u dead after this)
  scan9_kernel<<<dim3(24, 8, 4), 256, 0, stream>>>(u, dbl, xzb, alog, dtw, dtb, Dpw, y);
  // 6-7. biattn stats + gate
  lngm_kernel<<<dim3(16, 8, 4), 256, 0, stream>>>(y, G16);
  gate_kernel<<<dim3(8, 4), 384, 0, stream>>>(G16, lng, lnb, grw, grb, csw, csb, cbuf);
  // 8. dual GEMM with fused accgate (zeroes bnsum):
  //    out_proj (A = sum_i y_i*c_i on the fly) -> out[:,0:192]; pw1 -> hchb
  gemm_dualfuse<<<dim3(256, 3), 256, 0, stream>>>(
      y, cbuf, opwb, out, xb + 192, pw1wb, pw1b, hchb, bnsum);
  // 9. local branch: GLU+dwconv+BN stats
  gludwbn_kernel<<<dim3(64, 8), 192, 0, stream>>>(hchb, dww, dwb, h2, bnsum);
  // 10. pw2 with fused BN+silu -> out[:, 192:384]
  gemm_pw2<<<dim3(128, 3), 256, 0, stream>>>(h2, bnsum, bng, bnb, pw2wb, pw2b, out);
}

// Round 12
// 304.510 us; speedup vs baseline: 1.0360x; 1.0258x over previous
//
#include <hip/hip_runtime.h>
#include <stdint.h>

// MixMamba forward, MI355X. Round 22: R11 config (312.4, verified) + convdbl
// re-tiled to 32 rows: conv window [35][392] (27.4KB), conv result held in
// registers then written in-place into LDS as the u-tile; GEMM phase reads
// A-fragments straight from LDS (2-way bank alias = free), no global u
// re-read, no As staging. LDS 60->40KB (4 blocks/CU), grid 512->1024.
// B=8, L=1024 (32x32), MAMBA_DIM=192, D_INNER=384, D_STATE=16, D_CONV=4,
// DT_RANK=12, NDIR=4, RED=48, INNER_C=192, K_C=8.

#define DEV __device__ __forceinline__

typedef __attribute__((ext_vector_type(8))) short short8;
typedef __attribute__((ext_vector_type(4))) short short4v;
typedef __attribute__((ext_vector_type(4))) float f32x4;

DEV float bf(ushort v) { union { uint32_t u; float f; } c; c.u = ((uint32_t)v) << 16; return c.f; }
DEV ushort fbf(float f) {
  union { float f; uint32_t u; } c; c.f = f;
  uint32_t u = c.u;
  return (ushort)((u + 0x7FFFu + ((u >> 16) & 1u)) >> 16);  // RNE
}

#if __has_builtin(__builtin_amdgcn_exp2f)
DEV float fexp2(float x) { return __builtin_amdgcn_exp2f(x); }  // raw v_exp_f32
#else
DEV float fexp2(float x) { return __expf(x * 0.6931471805599453f); }
#endif

// lane-row (16) rotation add via DPP: x + ror<K>(x); pure VALU, no DS traffic
template<int CTRL>
DEV float rradd(float x) {
  return x + __int_as_float(__builtin_amdgcn_update_dpp(
      0, __float_as_int(x), CTRL, 0xF, 0xF, true));
}

// dir-space index j -> original L index (involution)
DEV int pmap(int i, int j) {
  if (i == 0) return j;
  if (i == 1) return 1023 - j;
  if (i == 2) return ((j & 31) << 5) | (j >> 5);
  int k = 1023 - j; return ((k & 31) << 5) | (k >> 5);
}

DEV void cvt4(const float* __restrict__ s, ushort* __restrict__ d, int blk, int tid) {
  const int idx = (blk * 256 + tid) * 4;
  float4 v = *(const float4*)(s + idx);
  d[idx] = fbf(v.x); d[idx + 1] = fbf(v.y); d[idx + 2] = fbf(v.z); d[idx + 3] = fbf(v.w);
}

// ---------------- all input conversions + xproj pad in ONE launch (3652 blocks)
__global__ __launch_bounds__(256) void prep_all(
    const float* __restrict__ x, ushort* __restrict__ xb,
    const float* __restrict__ ipw, ushort* __restrict__ ipwb,
    const float* __restrict__ opw, ushort* __restrict__ opwb,
    const float* __restrict__ pw1w, ushort* __restrict__ pw1wb,
    const float* __restrict__ pw2w, ushort* __restrict__ pw2wb,
    const float* __restrict__ xw, ushort* __restrict__ xwp)
{
  const int bx = blockIdx.x, tid = threadIdx.x;
  if (bx < 3072)      cvt4(x, xb, bx, tid);                 // 3145728
  else if (bx < 3216) cvt4(ipw, ipwb, bx - 3072, tid);      // 147456
  else if (bx < 3288) cvt4(opw, opwb, bx - 3216, tid);      // 73728
  else if (bx < 3360) cvt4(pw1w, pw1wb, bx - 3288, tid);    // 73728
  else if (bx < 3396) cvt4(pw2w, pw2wb, bx - 3360, tid);    // 36864
  else {                                                    // pad xproj (4,44,384)->(4,64,384)
    const int row = bx - 3396;             // i*64+n
    const int i = row >> 6, nn = row & 63;
    for (int c = tid; c < 384; c += 256)
      xwp[(size_t)row * 384 + c] = (nn < 44) ? fbf(xw[((size_t)i * 44 + nn) * 384 + c]) : (ushort)0;
  }
}

// ---------------- MFMA GEMM: C[M x N] = A[M x K] * Bw[N x K]^T (+bias), z-batched
template<bool BF16OUT, bool BIAS>
__global__ __launch_bounds__(256) void gemm_bt(
    const ushort* __restrict__ A, long long sAz, int lda,
    const ushort* __restrict__ Bw, long long sBz,
    const float* __restrict__ bias,
    void* __restrict__ C, long long sCz, int ldc, int coff, int K)
{
  __shared__ ushort As[64][40];
  __shared__ ushort Bs[64][40];
  A += (size_t)blockIdx.z * sAz;
  Bw += (size_t)blockIdx.z * sBz;
  const int tid = threadIdx.x;
  const int m0 = blockIdx.x * 64, n0 = blockIdx.y * 64;
  const int w = tid >> 6, lane = tid & 63, l15 = lane & 15, quad = lane >> 4;
  const int sr = tid >> 2, sc = (tid & 3) * 8;
  f32x4 acc[4] = {};
  for (int k0 = 0; k0 < K; k0 += 32) {
    __syncthreads();
    *(short8*)&As[sr][sc] = *(const short8*)(A + (size_t)(m0 + sr) * lda + k0 + sc);
    *(short8*)&Bs[sr][sc] = *(const short8*)(Bw + (size_t)(n0 + sr) * K + k0 + sc);
    __syncthreads();
    short8 av = *(short8*)&As[w * 16 + l15][quad * 8];
#pragma unroll
    for (int nt = 0; nt < 4; nt++) {
      short8 bv = *(short8*)&Bs[nt * 16 + l15][quad * 8];
      acc[nt] = __builtin_amdgcn_mfma_f32_16x16x32_bf16(av, bv, acc[nt], 0, 0, 0);
    }
  }
  float* cf = (float*)C + (size_t)blockIdx.z * sCz;
  ushort* cb = (ushort*)C + (size_t)blockIdx.z * sCz;
#pragma unroll
  for (int nt = 0; nt < 4; nt++) {
    const int col = n0 + nt * 16 + l15;
    const float bv = BIAS ? bias[col] : 0.f;
#pragma unroll
    for (int r = 0; r < 4; r++) {
      const int row = m0 + w * 16 + quad * 4 + r;
      float v = acc[nt][r] + bv;
      if (BF16OUT) cb[(size_t)row * ldc + coff + col] = fbf(v);
      else         cf[(size_t)row * ldc + coff + col] = v;
    }
  }
}

// ---------------- dual GEMM with fused accgate on the out_proj A operand.
// Grid (256, 3), 32x192 tiles, 4 waves (2 row-halves x 2 nt-groups of 6).
__global__ __launch_bounds__(256) void gemm_dualfuse(
    const ushort* __restrict__ yv, const float* __restrict__ cbuf,
    const ushort* __restrict__ B0, float* __restrict__ C0,
    const ushort* __restrict__ A1, const ushort* __restrict__ B1,
    const float* __restrict__ bias1, ushort* __restrict__ C1,
    float* __restrict__ bnsum)
{
  __shared__ ushort As[32][40];
  __shared__ ushort Bs[192][40];
  __shared__ float scb[4 * 384];
  if (blockIdx.x == 0 && blockIdx.y == 0) {
    for (int k = threadIdx.x; k < 384; k += 256) bnsum[k] = 0.f;
  }
  const int tid = threadIdx.x;
  const int m0 = blockIdx.x * 32;
  const int w = tid >> 6, lane = tid & 63, l15 = lane & 15, quad = lane >> 4;
  const int mrow = (w & 1) * 16, ntb = (w >> 1) * 6;
  const int brow = tid >> 2, bcol = (tid & 3) * 8;
  const int cfg0 = (blockIdx.y == 0);
  const int b = m0 >> 10;
  const ushort* Bw; int K, n0;
  if (cfg0) {
    Bw = B0; K = 384; n0 = 0;
    for (int k = tid; k < 1536; k += 256)
      scb[k] = cbuf[(size_t)((k / 384) * 8 + b) * 384 + (k % 384)];
  } else {
    Bw = B1; K = 192; n0 = (blockIdx.y - 1) * 192;
  }
  f32x4 acc[6] = {};
  for (int k0 = 0; k0 < K; k0 += 32) {
    __syncthreads();           // first pass also makes scb visible
    if (tid < 128) {
      const int row = m0 + brow, kc = k0 + bcol;
      if (cfg0) {
        float a8[8] = {};
#pragma unroll
        for (int i = 0; i < 4; i++) {
          const short8 v = *(const short8*)(yv + ((size_t)i * 8192 + row) * 384 + kc);
          const float* cv = &scb[i * 384 + kc];
#pragma unroll
          for (int k = 0; k < 8; k++) a8[k] += bf((ushort)v[k]) * cv[k];
        }
        short8 o;
#pragma unroll
        for (int k = 0; k < 8; k++) o[k] = (short)fbf(a8[k]);
        *(short8*)&As[brow][bcol] = o;
      } else {
        *(short8*)&As[brow][bcol] = *(const short8*)(A1 + (size_t)row * 384 + kc);
      }
    }
#pragma unroll
    for (int rr = 0; rr < 3; rr++)
      *(short8*)&Bs[brow + rr * 64][bcol] =
          *(const short8*)(Bw + (size_t)(n0 + brow + rr * 64) * K + k0 + bcol);
    __syncthreads();
    short8 av = *(short8*)&As[mrow + l15][quad * 8];
#pragma unroll
    for (int j = 0; j < 6; j++) {
      short8 bv = *(short8*)&Bs[(ntb + j) * 16 + l15][quad * 8];
      acc[j] = __builtin_amdgcn_mfma_f32_16x16x32_bf16(av, bv, acc[j], 0, 0, 0);
    }
  }
#pragma unroll
  for (int j = 0; j < 6; j++) {
    const int col = n0 + (ntb + j) * 16 + l15;
#pragma unroll
    for (int r = 0; r < 4; r++) {
      const int row = m0 + mrow + quad * 4 + r;
      if (cfg0) C0[(size_t)row * 384 + col] = acc[j][r];
      else      C1[(size_t)row * 384 + col] = fbf(acc[j][r] + bias1[col]);
    }
  }
}

// ---------------- pw2 GEMM with fused BN-normalize + silu on the A operand.
__global__ __launch_bounds__(256) void gemm_pw2(
    const float* __restrict__ h2, const float* __restrict__ bnsum,
    const float* __restrict__ bng, const float* __restrict__ bnb,
    const ushort* __restrict__ Bw, const float* __restrict__ bias,
    float* __restrict__ C)
{
  __shared__ ushort As[64][40];
  __shared__ ushort Bs[64][40];
  __shared__ float bsc[192], bsh[192];
  const int tid = threadIdx.x;
  const int m0 = blockIdx.x * 64, n0 = blockIdx.y * 64;
  const int w = tid >> 6, lane = tid & 63, l15 = lane & 15, quad = lane >> 4;
  const int sr = tid >> 2, sc = (tid & 3) * 8;
  for (int cth = tid; cth < 192; cth += 256) {
    float m = bnsum[cth] * (1.f / 8192.f);
    float va = bnsum[192 + cth] * (1.f / 8192.f) - m * m;
    float s = bng[cth] * rsqrtf(va + 1e-5f);
    bsc[cth] = s; bsh[cth] = bnb[cth] - m * s;
  }
  f32x4 acc[4] = {};
  for (int k0 = 0; k0 < 192; k0 += 32) {
    __syncthreads();           // also makes bsc/bsh visible on first pass
    {
      const float* hr = h2 + (size_t)(m0 + sr) * 192 + k0 + sc;
      f32x4 a0 = *(const f32x4*)(hr);
      f32x4 a1 = *(const f32x4*)(hr + 4);
      short8 v;
#pragma unroll
      for (int k = 0; k < 8; k++) {
        const float xx = (k < 4) ? a0[k] : a1[k - 4];
        const float xn = xx * bsc[k0 + sc + k] + bsh[k0 + sc + k];
        v[k] = (short)fbf(xn / (1.f + __expf(-xn)));
      }
      *(short8*)&As[sr][sc] = v;
    }
    *(short8*)&Bs[sr][sc] = *(const short8*)(Bw + (size_t)(n0 + sr) * 192 + k0 + sc);
    __syncthreads();
    short8 av = *(short8*)&As[w * 16 + l15][quad * 8];
#pragma unroll
    for (int nt = 0; nt < 4; nt++) {
      short8 bv = *(short8*)&Bs[nt * 16 + l15][quad * 8];
      acc[nt] = __builtin_amdgcn_mfma_f32_16x16x32_bf16(av, bv, acc[nt], 0, 0, 0);
    }
  }
#pragma unroll
  for (int nt = 0; nt < 4; nt++) {
    const int col = n0 + nt * 16 + l15;
    const float bv = bias[col];
#pragma unroll
    for (int r = 0; r < 4; r++) {
      const int row = m0 + w * 16 + quad * 4 + r;
      C[(size_t)row * 384 + 192 + col] = acc[nt][r] + bv;
    }
  }
}

// ---------------- convdbl32: conv (k=4, causal, silu) + dbl GEMM, 32-row tile.
// Conv result held in registers, window LDS reused in place as the u-tile;
// GEMM A-fragments read straight from LDS (row stride 784B = 2-way alias, free).
// Grid (256, 4), 256 threads.
__global__ __launch_bounds__(256) void convdbl32_kernel(
    const ushort* __restrict__ xzb, const float* __restrict__ cw,
    const float* __restrict__ cb, const ushort* __restrict__ xwp,
    ushort* __restrict__ u, float* __restrict__ dbl)
{
  __shared__ __align__(16) ushort sxz[35][392];   // 27.4 KB window -> u-tile
  __shared__ ushort Bs[64][40];                   // 5 KB
  __shared__ float swt[384][4];                   // 6 KB
  __shared__ float scb[384];                      // 1.5 KB
  const int tid = threadIdx.x;
  const int i = blockIdx.y;
  const int m0 = blockIdx.x * 32;
  const int b = m0 >> 10, j0 = m0 & 1023;

  // ---- stage conv weights + 35-row pmap'd window
  for (int k = tid; k < 1536; k += 256) ((float*)swt)[k] = cw[(size_t)i * 1536 + k];
  for (int k = tid; k < 384; k += 256) scb[k] = cb[i * 384 + k];
  for (int g = tid; g < 35 * 96; g += 256) {
    const int rr = g / 96, c4 = (g % 96) * 4;
    const int jj = j0 - 3 + rr;
    short4v v = {};
    if (jj >= 0)
      v = *(const short4v*)(xzb + (size_t)((b << 10) + pmap(i, jj)) * 768 + c4);
    *(short4v*)&sxz[rr][c4] = v;
  }
  __syncthreads();
  // ---- conv: thread (r=tid>>3, cp=tid&7) does cols cp*4 + q*32, q<12.
  //      Result -> global u (coalesced 64B/row-group) + registers for the u-tile.
  short4v ureg[12];
  {
    const int r = tid >> 3, cp = tid & 7;
    ushort* ur = u + ((size_t)((i * 8 + b) << 10) + j0 + r) * 384 + cp * 4;
#pragma unroll
    for (int q = 0; q < 12; q++) {
      const int c = cp * 4 + q * 32;
      const short4v x0 = *(const short4v*)&sxz[r + 0][c];
      const short4v x1 = *(const short4v*)&sxz[r + 1][c];
      const short4v x2 = *(const short4v*)&sxz[r + 2][c];
      const short4v x3 = *(const short4v*)&sxz[r + 3][c];
      short4v o;
#pragma unroll
      for (int j = 0; j < 4; j++) {
        const f32x4 wv = *(const f32x4*)&swt[c + j][0];
        float s = bf((ushort)x0[j]) * wv[0] + bf((ushort)x1[j]) * wv[1]
                + bf((ushort)x2[j]) * wv[2] + bf((ushort)x3[j]) * wv[3] + scb[c + j];
        o[j] = (short)fbf(s / (1.f + __expf(-s)));
      }
      *(short4v*)(ur + q * 32) = o;
      ureg[q] = o;
    }
  }
  __syncthreads();   // all conv reads of the window complete
  // ---- overwrite window rows 0..31 with the u-tile
  {
    const int r = tid >> 3, cp = tid & 7;
#pragma unroll
    for (int q = 0; q < 12; q++)
      *(short4v*)&sxz[r][cp * 4 + q * 32] = ureg[q];
  }
  // ---- GEMM: dbl[m0..m0+31][0..63] = u_tile @ xwp^T (K=384).
  //      4 waves: mrow=(w&1)*16, nt pair (w>>1)*2; acc[2].
  const ushort* Bw = xwp + (size_t)i * 64 * 384;
  const int w = tid >> 6, lane = tid & 63, l15 = lane & 15, quad = lane >> 4;
  const int mrow = (w & 1) * 16, npr = (w >> 1) * 2;
  const int brow = tid >> 2, bcol = (tid & 3) * 8;
  f32x4 acc[2] = {};
  for (int k0 = 0; k0 < 384; k0 += 32) {
    __syncthreads();   // first pass also fences the u-tile writes
    *(short8*)&Bs[brow][bcol] = *(const short8*)(Bw + (size_t)brow * 384 + k0 + bcol);
    __syncthreads();
    short8 av = *(short8*)&sxz[mrow + l15][k0 + quad * 8];
#pragma unroll
    for (int j = 0; j < 2; j++) {
      short8 bv = *(short8*)&Bs[(npr + j) * 16 + l15][quad * 8];
      acc[j] = __builtin_amdgcn_mfma_f32_16x16x32_bf16(av, bv, acc[j], 0, 0, 0);
    }
  }
  float* cf = dbl + (size_t)i * 8192 * 64;
#pragma unroll
  for (int j = 0; j < 2; j++) {
    const int col = (npr + j) * 16 + l15;
#pragma unroll
    for (int r = 0; r < 4; r++) {
      const int row = m0 + mrow + quad * 4 + r;
      cf[(size_t)row * 64 + col] = acc[j][r];
    }
  }
}

// ---------------- scan9: register-resident u/z/dt, 2 barriers/chunk, prefetch.
// grid (24, 8, 4), block 256 (16 ch x 16 states). 16 chunks of 64 steps.
#define NCH 16
#define CJ 64
__global__ __launch_bounds__(256, 3) void scan9_kernel(
    const ushort* __restrict__ u,     // [(i*8+b)*1024 + j][384] bf16
    const float*  __restrict__ dbl,   // [(i*8+b)*1024 + j][64]  f32 (dt12 B16 C16 pad)
    const ushort* __restrict__ xzb,   // [b*1024 + l][768] bf16 (z at +384)
    const float* __restrict__ alog, const float* __restrict__ dtw,
    const float* __restrict__ dtb, const float* __restrict__ Dpw,
    ushort* __restrict__ y)           // gated output
{
  const int dt0 = blockIdx.x * NCH;
  const int b = blockIdx.y, i = blockIdx.z;
  const int tid = threadIdx.x;
  const int ch = tid >> 4, n = tid & 15;
  const int srow = tid >> 2, role = tid & 3;

  __shared__ float sbc[CJ / 2][68];    // [jp][4n+2e+{0,1}] = B_n(2jp+e), C_n(2jp+e)
  __shared__ float sdu[CJ / 2][68];    // [jp][4ch+2e+{0,1}] = dl(2jp+e), dl*u(2jp+e)
  __shared__ float sy[CJ][20];         // p per (t, ch)
  __shared__ float sDp[NCH];

  float w48[4][12], dtbv4[4];
#pragma unroll
  for (int cc = 0; cc < 4; cc++) {
    const int chp = 4 * role + cc;
#pragma unroll
    for (int r = 0; r < 12; r++) w48[cc][r] = dtw[((size_t)i * 384 + dt0 + chp) * 12 + r];
    dtbv4[cc] = dtb[i * 384 + dt0 + chp];
  }
  const float L2E = 1.4426950408889634f;
  const float Al = -__expf(alog[((size_t)i * 384 + dt0 + ch) * 16 + n]) * L2E;
  if (tid < NCH) sDp[tid] = Dpw[i * 384 + dt0 + tid];

  // fma-mask: lane n collects step s (within q-block) iff (n>>2)==(s&3)
  const float selm[4] = { (n >> 2) == 0 ? 1.f : 0.f, (n >> 2) == 1 ? 1.f : 0.f,
                          (n >> 2) == 2 ? 1.f : 0.f, (n >> 2) == 3 ? 1.f : 0.f };

  const size_t rb = (size_t)(i * 8 + b) << 10;
  const ushort* ub = u + rb * 384 + dt0;
  const float* dblb = dbl + rb * 64;
  const ushort* zb = xzb + ((size_t)b << 10) * 768 + 384 + dt0;
  ushort* yb = y + rb * 384 + dt0;
  const float* sdup = &sdu[0][4 * ch];
  const float* sbcp = &sbc[0][4 * n];

  // ---- prefetch chunk 0 inputs into registers
  f32x4 nd0, nd1, nd2, ns0, ns1, ns2; short4v nu, nz;
  {
    const float* src = dblb + (size_t)srow * 64;
    nd0 = *(const f32x4*)(src); nd1 = *(const f32x4*)(src + 4); nd2 = *(const f32x4*)(src + 8);
    const float* seg = src + role * 12;
    ns0 = *(const f32x4*)(seg); ns1 = *(const f32x4*)(seg + 4); ns2 = *(const f32x4*)(seg + 8);
    nu = *(const short4v*)(ub + (size_t)srow * 384 + 4 * role);
    nz = *(const short4v*)(zb + (size_t)pmap(i, srow) * 768 + 4 * role);
  }

  float h = 0.f;

  for (int c = 0; c < 16; c++) {
    const int j0 = c * CJ;
    // ---- convert this chunk's u/z (registers; also used by epilogue)
    f32x4 uf, zf;
#pragma unroll
    for (int k = 0; k < 4; k++) { uf[k] = bf((ushort)nu[k]); zf[k] = bf((ushort)nz[k]); }
    // ---- (a) B/C transpose scatter from register segment (roles 1-3)
    if (role != 0) {
      float vals[12];
#pragma unroll
      for (int k = 0; k < 4; k++) { vals[k] = ns0[k]; vals[4 + k] = ns1[k]; vals[8 + k] = ns2[k]; }
#pragma unroll
      for (int k = 0; k < 12; k++) {
        const int f = role * 12 + k;
        if (f < 44) {
          const int isC = (f >= 28) ? 1 : 0;
          const int nn = isC ? (f - 28) : (f - 12);
          sbc[srow >> 1][4 * nn + 2 * (srow & 1) + isC] = vals[k];
        }
      }
    }
    // ---- (c) delta from register dt (fast softplus), store (dl, dl*u) pairs
    {
      float dtr[12];
#pragma unroll
      for (int k = 0; k < 4; k++) { dtr[k] = nd0[k]; dtr[4 + k] = nd1[k]; dtr[8 + k] = nd2[k]; }
#pragma unroll
      for (int cc = 0; cc < 4; cc++) {
        float s = dtbv4[cc];
#pragma unroll
        for (int r = 0; r < 12; r++) s += dtr[r] * w48[cc][r];
        const float dl = fmaxf(s, 0.f) + __logf(1.f + __expf(-fabsf(s)));
        float2 pr; pr.x = dl; pr.y = dl * uf[cc];
        *(float2*)&sdu[srow >> 1][4 * (4 * role + cc) + 2 * (srow & 1)] = pr;
      }
    }
    __syncthreads();   // S1: sbc + sdu ready; prev epilogue's sy reads complete
    // ---- T14 prefetch: issue chunk c+1 global loads; latency hides under (d)
    {
      const int cn = (c < 15) ? (c + 1) : 0;          // clamp: redundant reload ok
      const int rown = cn * CJ + srow;
      const float* src = dblb + (size_t)rown * 64;
      nd0 = *(const f32x4*)(src); nd1 = *(const f32x4*)(src + 4); nd2 = *(const f32x4*)(src + 8);
      const float* seg = src + role * 12;
      ns0 = *(const f32x4*)(seg); ns1 = *(const f32x4*)(seg + 4); ns2 = *(const f32x4*)(seg + 8);
      nu = *(const short4v*)(ub + (size_t)rown * 384 + 4 * role);
      nz = *(const short4v*)(zb + (size_t)pmap(i, rown) * 768 + 4 * role);
    }
    // ---- (d) serial 64 steps in 4 q-blocks of 16
#pragma unroll
    for (int q = 0; q < 4; q++) {
      f32x4 pq = {0.f, 0.f, 0.f, 0.f};
#pragma unroll
      for (int s2 = 0; s2 < 8; s2++) {
        const f32x4 duP = *(const f32x4*)(sdup + (q * 8 + s2) * 68);
        const f32x4 bcP = *(const f32x4*)(sbcp + (q * 8 + s2) * 68);
        {
          const float e = fexp2(duP[0] * Al);
          h = e * h + duP[1] * bcP[0];
          float p = h * bcP[1];
          p = rradd<0x124>(p); p = rradd<0x128>(p);          // T_{n&3}
          pq[s2 >> 1] = fmaf(selm[(2 * s2) & 3], p, pq[s2 >> 1]);
        }
        {
          const float e = fexp2(duP[2] * Al);
          h = e * h + duP[3] * bcP[2];
          float p = h * bcP[3];
          p = rradd<0x124>(p); p = rradd<0x128>(p);
          pq[s2 >> 1] = fmaf(selm[(2 * s2 + 1) & 3], p, pq[s2 >> 1]);
        }
      }
#pragma unroll
      for (int j = 0; j < 4; j++) {
        float t2 = rradd<0xB1>(pq[j]);   // quad_perm [1,0,3,2]  (xor 1)
        t2 = rradd<0x4E>(t2);            // quad_perm [2,3,0,1]  (xor 2)
        if ((n & 3) == 0) sy[(q << 4) | (j << 2) | (n >> 2)][ch] = t2;
      }
    }
    __syncthreads();   // S2: sy ready; (d) done reading sbc/sdu for next iter
    // ---- (e) epilogue: gate with silu(z), add u*Dp, coalesced 8B stores
    {
      const int lo = pmap(i, j0 + srow);
      const f32x4 y4 = *(const f32x4*)&sy[srow][role * 4];
      short4v o;
#pragma unroll
      for (int t = 0; t < 4; t++) {
        const float z = zf[t];
        const float val = (y4[t] + uf[t] * sDp[role * 4 + t]) * (z / (1.f + __expf(-z)));
        o[t] = (short)fbf(val);
      }
      *(short4v*)(yb + (size_t)lo * 384 + role * 4) = o;
    }
  }
}

// ---------------- fused LN stats + column partial means, LDS-staged slab.
__global__ __launch_bounds__(256) void lngm_kernel(const ushort* __restrict__ y,
                                                   float* __restrict__ G16)
{
  const int slab = blockIdx.x, b = blockIdx.y, i = blockIdx.z;
  const int tid = threadIdx.x;
  const int w = tid >> 6, lane = tid & 63;
  __shared__ float smu[64], srs[64];
  __shared__ ushort sy16[64][384];     // 48 KB
  const size_t base = (size_t)i * 8192 + b * 1024 + slab * 64;
  for (int rr = 0; rr < 16; rr++) {
    const int r = w * 16 + rr;
    const ushort* yr = y + (base + r) * 384;
    const short4v v4 = *(const short4v*)(yr + 4 * lane);         // elems 0..255
    const uint32_t v2 = *(const uint32_t*)(yr + 256 + 2 * lane); // elems 256..383
    *(short4v*)&sy16[r][4 * lane] = v4;
    *(uint32_t*)&sy16[r][256 + 2 * lane] = v2;
    float s = 0.f, ss = 0.f;
#pragma unroll
    for (int t = 0; t < 4; t++) { float v = bf((ushort)v4[t]); s += v; ss += v * v; }
    { float v = bf((ushort)(v2 & 0xffffu)); s += v; ss += v * v; }
    { float v = bf((ushort)(v2 >> 16));     s += v; ss += v * v; }
#pragma unroll
    for (int off = 1; off < 64; off <<= 1) { s += __shfl_xor(s, off, 64); ss += __shfl_xor(ss, off, 64); }
    if (lane == 0) {
      float m = s * (1.f / 384.f);
      float va = ss * (1.f / 384.f) - m * m;
      smu[r] = m;
      srs[r] = rsqrtf(va + 1e-5f);
    }
  }
  __syncthreads();
  if (tid < 192) {
    const int c0 = tid * 2;
    float s0 = 0.f, s1 = 0.f;
#pragma unroll 8
    for (int r = 0; r < 64; r++) {
      const uint32_t pv = *(const uint32_t*)&sy16[r][c0];
      const float rs = srs[r], mu = smu[r];
      s0 += (bf((ushort)(pv & 0xffffu)) - mu) * rs;
      s1 += (bf((ushort)(pv >> 16)) - mu) * rs;
    }
    float* g = G16 + ((size_t)(i * 8 + b) * 16 + slab) * 384 + c0;
    g[0] = s0; g[1] = s1;
  }
}

// ---------------- biattn gate, 384 threads: slab-sum 1 col/thread; gr GEMV
// split 8 lanes/row (48 MACs + 8-lane shuffle reduce); cs GEMV 1 out/thread.
__global__ __launch_bounds__(384) void gate_kernel(const float* __restrict__ G16,
    const float* __restrict__ lng, const float* __restrict__ lnb,
    const float* __restrict__ grw, const float* __restrict__ grb,
    const float* __restrict__ csw, const float* __restrict__ csb, float* __restrict__ cbuf)
{
  const int b = blockIdx.x, i = blockIdx.y;
  const int ib = i * 8 + b;
  const int t = threadIdx.x;
  __shared__ float sG[384];
  __shared__ float g48[48];
  {
    const float* g = G16 + (size_t)ib * 16 * 384 + t;
    float s = 0.f;
#pragma unroll
    for (int k = 0; k < 16; k++) s += g[k * 384];
    sG[t] = s * (1.f / 1024.f) * lng[t] + lnb[t];
  }
  __syncthreads();
  {
    const int row = t >> 3, seg = t & 7;      // 48 rows x 8 segs
    const float* wr = grw + (size_t)row * 384 + seg * 48;
    const float* gr = sG + seg * 48;
    float s = 0.f;
#pragma unroll
    for (int k = 0; k < 48; k++) s += gr[k] * wr[k];
    s += __shfl_xor(s, 1, 64); s += __shfl_xor(s, 2, 64); s += __shfl_xor(s, 4, 64);
    if (seg == 0) {
      s += grb[row];
      g48[row] = 0.5f * s * (1.f + erff(s * 0.70710678118f));
    }
  }
  __syncthreads();
  {
    float s = csb[t];
#pragma unroll
    for (int r = 0; r < 48; r++) s += g48[r] * csw[(size_t)t * 48 + r];
    cbuf[(size_t)ib * 384 + t] = 1.f / (1.f + __expf(-s));
  }
}

// ---------------- local: fused GLU + dwconv(k=8, pad 4,3) + BN partial sums
__global__ __launch_bounds__(192) void gludwbn_kernel(const ushort* __restrict__ hchb,
    const float* __restrict__ dww, const float* __restrict__ dwb,
    float* __restrict__ h2, float* __restrict__ bnsum)
{
  const int c = threadIdx.x;           // 192
  const int lt = blockIdx.x, b = blockIdx.y;   // 16 rows per block
  __shared__ float sv[23][192];
  const int l0 = lt * 16;
#pragma unroll 4
  for (int r = 0; r < 23; r++) {
    const int ls = l0 + r - 4;
    float v = 0.f;
    if (ls >= 0 && ls < 1024) {
      const size_t rr = (size_t)((b << 10) + ls) * 384;
      const float a = bf(hchb[rr + c]);
      const float g = bf(hchb[rr + 192 + c]);
      v = a / (1.f + __expf(-g));
    }
    sv[r][c] = v;
  }
  __syncthreads();
  float wk[8];
#pragma unroll
  for (int k = 0; k < 8; k++) wk[k] = dww[(c << 3) + k];
  const float bias = dwb[c];
  float sacc = 0.f, ssacc = 0.f;
  for (int q = 0; q < 16; q++) {
    float s = bias;
#pragma unroll
    for (int k = 0; k < 8; k++) s += sv[q + k][c] * wk[k];
    h2[(size_t)((b << 10) + l0 + q) * 192 + c] = s;
    sacc += s; ssacc += s * s;
  }
  atomicAdd(&bnsum[c], sacc);
  atomicAdd(&bnsum[192 + c], ssacc);
}

extern "C" void kernel_launch(void* const* d_in, const int* in_sizes, int n_in,
                              void* d_out, int out_size, void* d_ws, size_t ws_size,
                              hipStream_t stream) {
  const float* x    = (const float*)d_in[0];
  const float* ipw  = (const float*)d_in[1];
  const float* alog = (const float*)d_in[2];
  const float* cw   = (const float*)d_in[3];
  const float* cbv  = (const float*)d_in[4];
  const float* xw   = (const float*)d_in[5];
  const float* dtw  = (const float*)d_in[6];
  const float* dtb  = (const float*)d_in[7];
  const float* Dpw  = (const float*)d_in[8];
  const float* opw  = (const float*)d_in[9];
  const float* lng  = (const float*)d_in[10];
  const float* lnb  = (const float*)d_in[11];
  const float* grw  = (const float*)d_in[12];
  const float* grb  = (const float*)d_in[13];
  const float* csw  = (const float*)d_in[14];
  const float* csb  = (const float*)d_in[15];
  const float* pw1w = (const float*)d_in[16];
  const float* pw1b = (const float*)d_in[17];
  const float* dww  = (const float*)d_in[18];
  const float* dwb  = (const float*)d_in[19];
  const float* bng  = (const float*)d_in[20];
  const float* bnb  = (const float*)d_in[21];
  const float* pw2w = (const float*)d_in[22];
  const float* pw2b = (const float*)d_in[23];
  float* out = (float*)d_out;

  char* ws = (char*)d_ws;
  // workspace (bytes); peak ~85.6 MB (proven safe by rounds 7-21)
  ushort* xb    = (ushort*)(ws + 0);          // 8192*384 bf16        6291456
  ushort* xzb   = (ushort*)(ws + 6291456);    // 8192*768 bf16       12582912
  ushort* u     = (ushort*)(ws + 18874368);   // 4*8192*384 bf16     25165824
  float*  dbl   = (float*)(ws + 44040192);    // 4*8192*64 f32        8388608
  ushort* y     = (ushort*)(ws + 52428800);   // 4*8192*384 bf16     25165824
  float*  G16   = (float*)(ws + 83886080);    // 32*16*384 f32         786432
  float*  cbuf  = (float*)(ws + 84672512);    // 32*384 f32             49152
  ushort* xwp   = (ushort*)(ws + 84721664);   // 4*64*384 bf16         196608
  ushort* ipwb  = (ushort*)(ws + 84918272);   // 768*192 bf16          294912
  ushort* opwb  = (ushort*)(ws + 85213184);   // 192*384 bf16          147456
  ushort* pw1wb = (ushort*)(ws + 85360640);   // 384*192 bf16          147456
  ushort* pw2wb = (ushort*)(ws + 85508096);   // 192*192 bf16           73728
  float*  bnsum = (float*)(ws + 85581824);    // 384 f32                 1536
  // local-branch aliases in u region (u dead after scan9)
  ushort* hchb = (ushort*)(ws + 18874368);    // 8192*384 bf16        6291456
  float*  h2   = (float*)(ws + 34603008);     // 8192*192 f32         6291456

  // 1. all conversions + pad
  prep_all<<<dim3(3652), 256, 0, stream>>>(x, xb, ipw, ipwb, opw, opwb,
                                           pw1w, pw1wb, pw2w, pw2wb, xw, xwp);
  // 2. xz = mamba_in @ in_proj_w^T (bf16), M=8192 K=192 N=768
  gemm_bt<true, false><<<dim3(128, 12, 1), 256, 0, stream>>>(
      xb, 0, 384, ipwb, 0, nullptr, xzb, 0, 768, 0, 192);
  // 3+4. fused conv + dbl GEMM (32-row tiles, u-tile kept in LDS)
  convdbl32_kernel<<<dim3(256, 4), 256, 0, stream>>>(xzb, cw, cbv, xwp, u, dbl);
  // 5. scan (u dead after this)
  scan9_kernel<<<dim3(24, 8, 4), 256, 0, stream>>>(u, dbl, xzb, alog, dtw, dtb, Dpw, y);
  // 6-7. biattn stats + gate
  lngm_kernel<<<dim3(16, 8, 4), 256, 0, stream>>>(y, G16);
  gate_kernel<<<dim3(8, 4), 384, 0, stream>>>(G16, lng, lnb, grw, grb, csw, csb, cbuf);
  // 8. dual GEMM with fused accgate (zeroes bnsum):
  //    out_proj (A = sum_i y_i*c_i on the fly) -> out[:,0:192]; pw1 -> hchb
  gemm_dualfuse<<<dim3(256, 3), 256, 0, stream>>>(
      y, cbuf, opwb, out, xb + 192, pw1wb, pw1b, hchb, bnsum);
  // 9. local branch: GLU+dwconv+BN stats
  gludwbn_kernel<<<dim3(64, 8), 192, 0, stream>>>(hchb, dww, dwb, h2, bnsum);
  // 10. pw2 with fused BN+silu -> out[:, 192:384]
  gemm_pw2<<<dim3(128, 3), 256, 0, stream>>>(h2, bnsum, bng, bnb, pw2wb, pw2b, out);
}

// Round 13
// 303.287 us; speedup vs baseline: 1.0401x; 1.0040x over previous
//
#include <hip/hip_runtime.h>
#include <stdint.h>

// MixMamba forward, MI355X. Round 23: xb eliminated — x is converted f32->bf16
// inside the consumers' LDS staging (xz GEMM cols 0:192, dualfuse-pw1 cols
// 192:384; bit-identical fbf), prep_all shrinks 3652->580 blocks (weights+pad
// only), -~25MB HBM. Everything else per R12-verified state (304.5 µs):
// scan9 floor, convdbl32, lngm-staged, gate384, dualfuse accgate, pw2 BN.
// B=8, L=1024 (32x32), MAMBA_DIM=192, D_INNER=384, D_STATE=16, D_CONV=4,
// DT_RANK=12, NDIR=4, RED=48, INNER_C=192, K_C=8.

#define DEV __device__ __forceinline__

typedef __attribute__((ext_vector_type(8))) short short8;
typedef __attribute__((ext_vector_type(4))) short short4v;
typedef __attribute__((ext_vector_type(4))) float f32x4;

DEV float bf(ushort v) { union { uint32_t u; float f; } c; c.u = ((uint32_t)v) << 16; return c.f; }
DEV ushort fbf(float f) {
  union { float f; uint32_t u; } c; c.f = f;
  uint32_t u = c.u;
  return (ushort)((u + 0x7FFFu + ((u >> 16) & 1u)) >> 16);  // RNE
}

#if __has_builtin(__builtin_amdgcn_exp2f)
DEV float fexp2(float x) { return __builtin_amdgcn_exp2f(x); }  // raw v_exp_f32
#else
DEV float fexp2(float x) { return __expf(x * 0.6931471805599453f); }
#endif

// lane-row (16) rotation add via DPP: x + ror<K>(x); pure VALU, no DS traffic
template<int CTRL>
DEV float rradd(float x) {
  return x + __int_as_float(__builtin_amdgcn_update_dpp(
      0, __float_as_int(x), CTRL, 0xF, 0xF, true));
}

// dir-space index j -> original L index (involution)
DEV int pmap(int i, int j) {
  if (i == 0) return j;
  if (i == 1) return 1023 - j;
  if (i == 2) return ((j & 31) << 5) | (j >> 5);
  int k = 1023 - j; return ((k & 31) << 5) | (k >> 5);
}

DEV void cvt4(const float* __restrict__ s, ushort* __restrict__ d, int blk, int tid) {
  const int idx = (blk * 256 + tid) * 4;
  float4 v = *(const float4*)(s + idx);
  d[idx] = fbf(v.x); d[idx + 1] = fbf(v.y); d[idx + 2] = fbf(v.z); d[idx + 3] = fbf(v.w);
}

// ---------------- weight conversions + xproj pad (580 blocks; x no longer staged)
__global__ __launch_bounds__(256) void prep_all(
    const float* __restrict__ ipw, ushort* __restrict__ ipwb,
    const float* __restrict__ opw, ushort* __restrict__ opwb,
    const float* __restrict__ pw1w, ushort* __restrict__ pw1wb,
    const float* __restrict__ pw2w, ushort* __restrict__ pw2wb,
    const float* __restrict__ xw, ushort* __restrict__ xwp)
{
  const int bx = blockIdx.x, tid = threadIdx.x;
  if (bx < 144)       cvt4(ipw, ipwb, bx, tid);             // 147456
  else if (bx < 216)  cvt4(opw, opwb, bx - 144, tid);       // 73728
  else if (bx < 288)  cvt4(pw1w, pw1wb, bx - 216, tid);     // 73728
  else if (bx < 324)  cvt4(pw2w, pw2wb, bx - 288, tid);     // 36864
  else {                                                    // pad xproj (4,44,384)->(4,64,384)
    const int row = bx - 324;              // i*64+n
    const int i = row >> 6, nn = row & 63;
    for (int c = tid; c < 384; c += 256)
      xwp[(size_t)row * 384 + c] = (nn < 44) ? fbf(xw[((size_t)i * 44 + nn) * 384 + c]) : (ushort)0;
  }
}

// ---------------- xz GEMM: xzb = x[:, 0:192] @ ipwb^T, f32 A converted in staging.
// Grid (128, 12), 64x64 tiles.
__global__ __launch_bounds__(256) void gemm_xz(
    const float* __restrict__ x,       // [8192][384] f32 (cols 0..191 used)
    const ushort* __restrict__ Bw,     // ipwb [768][192] bf16
    ushort* __restrict__ C)            // xzb [8192][768] bf16
{
  __shared__ ushort As[64][40];
  __shared__ ushort Bs[64][40];
  const int tid = threadIdx.x;
  const int m0 = blockIdx.x * 64, n0 = blockIdx.y * 64;
  const int w = tid >> 6, lane = tid & 63, l15 = lane & 15, quad = lane >> 4;
  const int sr = tid >> 2, sc = (tid & 3) * 8;
  f32x4 acc[4] = {};
  for (int k0 = 0; k0 < 192; k0 += 32) {
    __syncthreads();
    {
      const float* xr = x + (size_t)(m0 + sr) * 384 + k0 + sc;
      f32x4 a0 = *(const f32x4*)(xr);
      f32x4 a1 = *(const f32x4*)(xr + 4);
      short8 v;
#pragma unroll
      for (int k = 0; k < 8; k++) v[k] = (short)fbf((k < 4) ? a0[k] : a1[k - 4]);
      *(short8*)&As[sr][sc] = v;
    }
    *(short8*)&Bs[sr][sc] = *(const short8*)(Bw + (size_t)(n0 + sr) * 192 + k0 + sc);
    __syncthreads();
    short8 av = *(short8*)&As[w * 16 + l15][quad * 8];
#pragma unroll
    for (int nt = 0; nt < 4; nt++) {
      short8 bv = *(short8*)&Bs[nt * 16 + l15][quad * 8];
      acc[nt] = __builtin_amdgcn_mfma_f32_16x16x32_bf16(av, bv, acc[nt], 0, 0, 0);
    }
  }
#pragma unroll
  for (int nt = 0; nt < 4; nt++) {
    const int col = n0 + nt * 16 + l15;
#pragma unroll
    for (int r = 0; r < 4; r++) {
      const int row = m0 + w * 16 + quad * 4 + r;
      C[(size_t)row * 768 + col] = fbf(acc[nt][r]);
    }
  }
}

// ---------------- dual GEMM with fused accgate on the out_proj A operand.
// Grid (256, 3), 32x192 tiles. cfg1's A = x[:,192:384] f32, converted in staging.
__global__ __launch_bounds__(256) void gemm_dualfuse(
    const ushort* __restrict__ yv, const float* __restrict__ cbuf,
    const ushort* __restrict__ B0, float* __restrict__ C0,
    const float* __restrict__ A1f, const ushort* __restrict__ B1,
    const float* __restrict__ bias1, ushort* __restrict__ C1,
    float* __restrict__ bnsum)
{
  __shared__ ushort As[32][40];
  __shared__ ushort Bs[192][40];
  __shared__ float scb[4 * 384];
  if (blockIdx.x == 0 && blockIdx.y == 0) {
    for (int k = threadIdx.x; k < 384; k += 256) bnsum[k] = 0.f;
  }
  const int tid = threadIdx.x;
  const int m0 = blockIdx.x * 32;
  const int w = tid >> 6, lane = tid & 63, l15 = lane & 15, quad = lane >> 4;
  const int mrow = (w & 1) * 16, ntb = (w >> 1) * 6;
  const int brow = tid >> 2, bcol = (tid & 3) * 8;
  const int cfg0 = (blockIdx.y == 0);
  const int b = m0 >> 10;
  const ushort* Bw; int K, n0;
  if (cfg0) {
    Bw = B0; K = 384; n0 = 0;
    for (int k = tid; k < 1536; k += 256)
      scb[k] = cbuf[(size_t)((k / 384) * 8 + b) * 384 + (k % 384)];
  } else {
    Bw = B1; K = 192; n0 = (blockIdx.y - 1) * 192;
  }
  f32x4 acc[6] = {};
  for (int k0 = 0; k0 < K; k0 += 32) {
    __syncthreads();           // first pass also makes scb visible
    if (tid < 128) {
      const int row = m0 + brow, kc = k0 + bcol;
      if (cfg0) {
        float a8[8] = {};
#pragma unroll
        for (int i = 0; i < 4; i++) {
          const short8 v = *(const short8*)(yv + ((size_t)i * 8192 + row) * 384 + kc);
          const float* cv = &scb[i * 384 + kc];
#pragma unroll
          for (int k = 0; k < 8; k++) a8[k] += bf((ushort)v[k]) * cv[k];
        }
        short8 o;
#pragma unroll
        for (int k = 0; k < 8; k++) o[k] = (short)fbf(a8[k]);
        *(short8*)&As[brow][bcol] = o;
      } else {
        const float* xr = A1f + (size_t)row * 384 + kc;
        f32x4 a0 = *(const f32x4*)(xr);
        f32x4 a1 = *(const f32x4*)(xr + 4);
        short8 o;
#pragma unroll
        for (int k = 0; k < 8; k++) o[k] = (short)fbf((k < 4) ? a0[k] : a1[k - 4]);
        *(short8*)&As[brow][bcol] = o;
      }
    }
#pragma unroll
    for (int rr = 0; rr < 3; rr++)
      *(short8*)&Bs[brow + rr * 64][bcol] =
          *(const short8*)(Bw + (size_t)(n0 + brow + rr * 64) * K + k0 + bcol);
    __syncthreads();
    short8 av = *(short8*)&As[mrow + l15][quad * 8];
#pragma unroll
    for (int j = 0; j < 6; j++) {
      short8 bv = *(short8*)&Bs[(ntb + j) * 16 + l15][quad * 8];
      acc[j] = __builtin_amdgcn_mfma_f32_16x16x32_bf16(av, bv, acc[j], 0, 0, 0);
    }
  }
#pragma unroll
  for (int j = 0; j < 6; j++) {
    const int col = n0 + (ntb + j) * 16 + l15;
#pragma unroll
    for (int r = 0; r < 4; r++) {
      const int row = m0 + mrow + quad * 4 + r;
      if (cfg0) C0[(size_t)row * 384 + col] = acc[j][r];
      else      C1[(size_t)row * 384 + col] = fbf(acc[j][r] + bias1[col]);
    }
  }
}

// ---------------- pw2 GEMM with fused BN-normalize + silu on the A operand.
__global__ __launch_bounds__(256) void gemm_pw2(
    const float* __restrict__ h2, const float* __restrict__ bnsum,
    const float* __restrict__ bng, const float* __restrict__ bnb,
    const ushort* __restrict__ Bw, const float* __restrict__ bias,
    float* __restrict__ C)
{
  __shared__ ushort As[64][40];
  __shared__ ushort Bs[64][40];
  __shared__ float bsc[192], bsh[192];
  const int tid = threadIdx.x;
  const int m0 = blockIdx.x * 64, n0 = blockIdx.y * 64;
  const int w = tid >> 6, lane = tid & 63, l15 = lane & 15, quad = lane >> 4;
  const int sr = tid >> 2, sc = (tid & 3) * 8;
  for (int cth = tid; cth < 192; cth += 256) {
    float m = bnsum[cth] * (1.f / 8192.f);
    float va = bnsum[192 + cth] * (1.f / 8192.f) - m * m;
    float s = bng[cth] * rsqrtf(va + 1e-5f);
    bsc[cth] = s; bsh[cth] = bnb[cth] - m * s;
  }
  f32x4 acc[4] = {};
  for (int k0 = 0; k0 < 192; k0 += 32) {
    __syncthreads();           // also makes bsc/bsh visible on first pass
    {
      const float* hr = h2 + (size_t)(m0 + sr) * 192 + k0 + sc;
      f32x4 a0 = *(const f32x4*)(hr);
      f32x4 a1 = *(const f32x4*)(hr + 4);
      short8 v;
#pragma unroll
      for (int k = 0; k < 8; k++) {
        const float xx = (k < 4) ? a0[k] : a1[k - 4];
        const float xn = xx * bsc[k0 + sc + k] + bsh[k0 + sc + k];
        v[k] = (short)fbf(xn / (1.f + __expf(-xn)));
      }
      *(short8*)&As[sr][sc] = v;
    }
    *(short8*)&Bs[sr][sc] = *(const short8*)(Bw + (size_t)(n0 + sr) * 192 + k0 + sc);
    __syncthreads();
    short8 av = *(short8*)&As[w * 16 + l15][quad * 8];
#pragma unroll
    for (int nt = 0; nt < 4; nt++) {
      short8 bv = *(short8*)&Bs[nt * 16 + l15][quad * 8];
      acc[nt] = __builtin_amdgcn_mfma_f32_16x16x32_bf16(av, bv, acc[nt], 0, 0, 0);
    }
  }
#pragma unroll
  for (int nt = 0; nt < 4; nt++) {
    const int col = n0 + nt * 16 + l15;
    const float bv = bias[col];
#pragma unroll
    for (int r = 0; r < 4; r++) {
      const int row = m0 + w * 16 + quad * 4 + r;
      C[(size_t)row * 384 + 192 + col] = acc[nt][r] + bv;
    }
  }
}

// ---------------- convdbl32: conv (k=4, causal, silu) + dbl GEMM, 32-row tile.
__global__ __launch_bounds__(256) void convdbl32_kernel(
    const ushort* __restrict__ xzb, const float* __restrict__ cw,
    const float* __restrict__ cb, const ushort* __restrict__ xwp,
    ushort* __restrict__ u, float* __restrict__ dbl)
{
  __shared__ __align__(16) ushort sxz[35][392];   // 27.4 KB window -> u-tile
  __shared__ ushort Bs[64][40];                   // 5 KB
  __shared__ float swt[384][4];                   // 6 KB
  __shared__ float scb[384];                      // 1.5 KB
  const int tid = threadIdx.x;
  const int i = blockIdx.y;
  const int m0 = blockIdx.x * 32;
  const int b = m0 >> 10, j0 = m0 & 1023;

  // ---- stage conv weights + 35-row pmap'd window
  for (int k = tid; k < 1536; k += 256) ((float*)swt)[k] = cw[(size_t)i * 1536 + k];
  for (int k = tid; k < 384; k += 256) scb[k] = cb[i * 384 + k];
  for (int g = tid; g < 35 * 96; g += 256) {
    const int rr = g / 96, c4 = (g % 96) * 4;
    const int jj = j0 - 3 + rr;
    short4v v = {};
    if (jj >= 0)
      v = *(const short4v*)(xzb + (size_t)((b << 10) + pmap(i, jj)) * 768 + c4);
    *(short4v*)&sxz[rr][c4] = v;
  }
  __syncthreads();
  // ---- conv: thread (r=tid>>3, cp=tid&7) does cols cp*4 + q*32, q<12.
  short4v ureg[12];
  {
    const int r = tid >> 3, cp = tid & 7;
    ushort* ur = u + ((size_t)((i * 8 + b) << 10) + j0 + r) * 384 + cp * 4;
#pragma unroll
    for (int q = 0; q < 12; q++) {
      const int c = cp * 4 + q * 32;
      const short4v x0 = *(const short4v*)&sxz[r + 0][c];
      const short4v x1 = *(const short4v*)&sxz[r + 1][c];
      const short4v x2 = *(const short4v*)&sxz[r + 2][c];
      const short4v x3 = *(const short4v*)&sxz[r + 3][c];
      short4v o;
#pragma unroll
      for (int j = 0; j < 4; j++) {
        const f32x4 wv = *(const f32x4*)&swt[c + j][0];
        float s = bf((ushort)x0[j]) * wv[0] + bf((ushort)x1[j]) * wv[1]
                + bf((ushort)x2[j]) * wv[2] + bf((ushort)x3[j]) * wv[3] + scb[c + j];
        o[j] = (short)fbf(s / (1.f + __expf(-s)));
      }
      *(short4v*)(ur + q * 32) = o;
      ureg[q] = o;
    }
  }
  __syncthreads();   // all conv reads of the window complete
  // ---- overwrite window rows 0..31 with the u-tile
  {
    const int r = tid >> 3, cp = tid & 7;
#pragma unroll
    for (int q = 0; q < 12; q++)
      *(short4v*)&sxz[r][cp * 4 + q * 32] = ureg[q];
  }
  // ---- GEMM: dbl[m0..m0+31][0..63] = u_tile @ xwp^T (K=384).
  const ushort* Bw = xwp + (size_t)i * 64 * 384;
  const int w = tid >> 6, lane = tid & 63, l15 = lane & 15, quad = lane >> 4;
  const int mrow = (w & 1) * 16, npr = (w >> 1) * 2;
  const int brow = tid >> 2, bcol = (tid & 3) * 8;
  f32x4 acc[2] = {};
  for (int k0 = 0; k0 < 384; k0 += 32) {
    __syncthreads();   // first pass also fences the u-tile writes
    *(short8*)&Bs[brow][bcol] = *(const short8*)(Bw + (size_t)brow * 384 + k0 + bcol);
    __syncthreads();
    short8 av = *(short8*)&sxz[mrow + l15][k0 + quad * 8];
#pragma unroll
    for (int j = 0; j < 2; j++) {
      short8 bv = *(short8*)&Bs[(npr + j) * 16 + l15][quad * 8];
      acc[j] = __builtin_amdgcn_mfma_f32_16x16x32_bf16(av, bv, acc[j], 0, 0, 0);
    }
  }
  float* cf = dbl + (size_t)i * 8192 * 64;
#pragma unroll
  for (int j = 0; j < 2; j++) {
    const int col = (npr + j) * 16 + l15;
#pragma unroll
    for (int r = 0; r < 4; r++) {
      const int row = m0 + mrow + quad * 4 + r;
      cf[(size_t)row * 64 + col] = acc[j][r];
    }
  }
}

// ---------------- scan9: register-resident u/z/dt, 2 barriers/chunk, prefetch.
// grid (24, 8, 4), block 256 (16 ch x 16 states). 16 chunks of 64 steps.
#define NCH 16
#define CJ 64
__global__ __launch_bounds__(256, 3) void scan9_kernel(
    const ushort* __restrict__ u,     // [(i*8+b)*1024 + j][384] bf16
    const float*  __restrict__ dbl,   // [(i*8+b)*1024 + j][64]  f32 (dt12 B16 C16 pad)
    const ushort* __restrict__ xzb,   // [b*1024 + l][768] bf16 (z at +384)
    const float* __restrict__ alog, const float* __restrict__ dtw,
    const float* __restrict__ dtb, const float* __restrict__ Dpw,
    ushort* __restrict__ y)           // gated output
{
  const int dt0 = blockIdx.x * NCH;
  const int b = blockIdx.y, i = blockIdx.z;
  const int tid = threadIdx.x;
  const int ch = tid >> 4, n = tid & 15;
  const int srow = tid >> 2, role = tid & 3;

  __shared__ float sbc[CJ / 2][68];    // [jp][4n+2e+{0,1}] = B_n(2jp+e), C_n(2jp+e)
  __shared__ float sdu[CJ / 2][68];    // [jp][4ch+2e+{0,1}] = dl(2jp+e), dl*u(2jp+e)
  __shared__ float sy[CJ][20];         // p per (t, ch)
  __shared__ float sDp[NCH];

  float w48[4][12], dtbv4[4];
#pragma unroll
  for (int cc = 0; cc < 4; cc++) {
    const int chp = 4 * role + cc;
#pragma unroll
    for (int r = 0; r < 12; r++) w48[cc][r] = dtw[((size_t)i * 384 + dt0 + chp) * 12 + r];
    dtbv4[cc] = dtb[i * 384 + dt0 + chp];
  }
  const float L2E = 1.4426950408889634f;
  const float Al = -__expf(alog[((size_t)i * 384 + dt0 + ch) * 16 + n]) * L2E;
  if (tid < NCH) sDp[tid] = Dpw[i * 384 + dt0 + tid];

  // fma-mask: lane n collects step s (within q-block) iff (n>>2)==(s&3)
  const float selm[4] = { (n >> 2) == 0 ? 1.f : 0.f, (n >> 2) == 1 ? 1.f : 0.f,
                          (n >> 2) == 2 ? 1.f : 0.f, (n >> 2) == 3 ? 1.f : 0.f };

  const size_t rb = (size_t)(i * 8 + b) << 10;
  const ushort* ub = u + rb * 384 + dt0;
  const float* dblb = dbl + rb * 64;
  const ushort* zb = xzb + ((size_t)b << 10) * 768 + 384 + dt0;
  ushort* yb = y + rb * 384 + dt0;
  const float* sdup = &sdu[0][4 * ch];
  const float* sbcp = &sbc[0][4 * n];

  // ---- prefetch chunk 0 inputs into registers
  f32x4 nd0, nd1, nd2, ns0, ns1, ns2; short4v nu, nz;
  {
    const float* src = dblb + (size_t)srow * 64;
    nd0 = *(const f32x4*)(src); nd1 = *(const f32x4*)(src + 4); nd2 = *(const f32x4*)(src + 8);
    const float* seg = src + role * 12;
    ns0 = *(const f32x4*)(seg); ns1 = *(const f32x4*)(seg + 4); ns2 = *(const f32x4*)(seg + 8);
    nu = *(const short4v*)(ub + (size_t)srow * 384 + 4 * role);
    nz = *(const short4v*)(zb + (size_t)pmap(i, srow) * 768 + 4 * role);
  }

  float h = 0.f;

  for (int c = 0; c < 16; c++) {
    const int j0 = c * CJ;
    // ---- convert this chunk's u/z (registers; also used by epilogue)
    f32x4 uf, zf;
#pragma unroll
    for (int k = 0; k < 4; k++) { uf[k] = bf((ushort)nu[k]); zf[k] = bf((ushort)nz[k]); }
    // ---- (a) B/C transpose scatter from register segment (roles 1-3)
    if (role != 0) {
      float vals[12];
#pragma unroll
      for (int k = 0; k < 4; k++) { vals[k] = ns0[k]; vals[4 + k] = ns1[k]; vals[8 + k] = ns2[k]; }
#pragma unroll
      for (int k = 0; k < 12; k++) {
        const int f = role * 12 + k;
        if (f < 44) {
          const int isC = (f >= 28) ? 1 : 0;
          const int nn = isC ? (f - 28) : (f - 12);
          sbc[srow >> 1][4 * nn + 2 * (srow & 1) + isC] = vals[k];
        }
      }
    }
    // ---- (c) delta from register dt (fast softplus), store (dl, dl*u) pairs
    {
      float dtr[12];
#pragma unroll
      for (int k = 0; k < 4; k++) { dtr[k] = nd0[k]; dtr[4 + k] = nd1[k]; dtr[8 + k] = nd2[k]; }
#pragma unroll
      for (int cc = 0; cc < 4; cc++) {
        float s = dtbv4[cc];
#pragma unroll
        for (int r = 0; r < 12; r++) s += dtr[r] * w48[cc][r];
        const float dl = fmaxf(s, 0.f) + __logf(1.f + __expf(-fabsf(s)));
        float2 pr; pr.x = dl; pr.y = dl * uf[cc];
        *(float2*)&sdu[srow >> 1][4 * (4 * role + cc) + 2 * (srow & 1)] = pr;
      }
    }
    __syncthreads();   // S1: sbc + sdu ready; prev epilogue's sy reads complete
    // ---- T14 prefetch: issue chunk c+1 global loads; latency hides under (d)
    {
      const int cn = (c < 15) ? (c + 1) : 0;          // clamp: redundant reload ok
      const int rown = cn * CJ + srow;
      const float* src = dblb + (size_t)rown * 64;
      nd0 = *(const f32x4*)(src); nd1 = *(const f32x4*)(src + 4); nd2 = *(const f32x4*)(src + 8);
      const float* seg = src + role * 12;
      ns0 = *(const f32x4*)(seg); ns1 = *(const f32x4*)(seg + 4); ns2 = *(const f32x4*)(seg + 8);
      nu = *(const short4v*)(ub + (size_t)rown * 384 + 4 * role);
      nz = *(const short4v*)(zb + (size_t)pmap(i, rown) * 768 + 4 * role);
    }
    // ---- (d) serial 64 steps in 4 q-blocks of 16
#pragma unroll
    for (int q = 0; q < 4; q++) {
      f32x4 pq = {0.f, 0.f, 0.f, 0.f};
#pragma unroll
      for (int s2 = 0; s2 < 8; s2++) {
        const f32x4 duP = *(const f32x4*)(sdup + (q * 8 + s2) * 68);
        const f32x4 bcP = *(const f32x4*)(sbcp + (q * 8 + s2) * 68);
        {
          const float e = fexp2(duP[0] * Al);
          h = e * h + duP[1] * bcP[0];
          float p = h * bcP[1];
          p = rradd<0x124>(p); p = rradd<0x128>(p);          // T_{n&3}
          pq[s2 >> 1] = fmaf(selm[(2 * s2) & 3], p, pq[s2 >> 1]);
        }
        {
          const float e = fexp2(duP[2] * Al);
          h = e * h + duP[3] * bcP[2];
          float p = h * bcP[3];
          p = rradd<0x124>(p); p = rradd<0x128>(p);
          pq[s2 >> 1] = fmaf(selm[(2 * s2 + 1) & 3], p, pq[s2 >> 1]);
        }
      }
#pragma unroll
      for (int j = 0; j < 4; j++) {
        float t2 = rradd<0xB1>(pq[j]);   // quad_perm [1,0,3,2]  (xor 1)
        t2 = rradd<0x4E>(t2);            // quad_perm [2,3,0,1]  (xor 2)
        if ((n & 3) == 0) sy[(q << 4) | (j << 2) | (n >> 2)][ch] = t2;
      }
    }
    __syncthreads();   // S2: sy ready; (d) done reading sbc/sdu for next iter
    // ---- (e) epilogue: gate with silu(z), add u*Dp, coalesced 8B stores
    {
      const int lo = pmap(i, j0 + srow);
      const f32x4 y4 = *(const f32x4*)&sy[srow][role * 4];
      short4v o;
#pragma unroll
      for (int t = 0; t < 4; t++) {
        const float z = zf[t];
        const float val = (y4[t] + uf[t] * sDp[role * 4 + t]) * (z / (1.f + __expf(-z)));
        o[t] = (short)fbf(val);
      }
      *(short4v*)(yb + (size_t)lo * 384 + role * 4) = o;
    }
  }
}

// ---------------- fused LN stats + column partial means, LDS-staged slab.
__global__ __launch_bounds__(256) void lngm_kernel(const ushort* __restrict__ y,
                                                   float* __restrict__ G16)
{
  const int slab = blockIdx.x, b = blockIdx.y, i = blockIdx.z;
  const int tid = threadIdx.x;
  const int w = tid >> 6, lane = tid & 63;
  __shared__ float smu[64], srs[64];
  __shared__ ushort sy16[64][384];     // 48 KB
  const size_t base = (size_t)i * 8192 + b * 1024 + slab * 64;
  for (int rr = 0; rr < 16; rr++) {
    const int r = w * 16 + rr;
    const ushort* yr = y + (base + r) * 384;
    const short4v v4 = *(const short4v*)(yr + 4 * lane);         // elems 0..255
    const uint32_t v2 = *(const uint32_t*)(yr + 256 + 2 * lane); // elems 256..383
    *(short4v*)&sy16[r][4 * lane] = v4;
    *(uint32_t*)&sy16[r][256 + 2 * lane] = v2;
    float s = 0.f, ss = 0.f;
#pragma unroll
    for (int t = 0; t < 4; t++) { float v = bf((ushort)v4[t]); s += v; ss += v * v; }
    { float v = bf((ushort)(v2 & 0xffffu)); s += v; ss += v * v; }
    { float v = bf((ushort)(v2 >> 16));     s += v; ss += v * v; }
#pragma unroll
    for (int off = 1; off < 64; off <<= 1) { s += __shfl_xor(s, off, 64); ss += __shfl_xor(ss, off, 64); }
    if (lane == 0) {
      float m = s * (1.f / 384.f);
      float va = ss * (1.f / 384.f) - m * m;
      smu[r] = m;
      srs[r] = rsqrtf(va + 1e-5f);
    }
  }
  __syncthreads();
  if (tid < 192) {
    const int c0 = tid * 2;
    float s0 = 0.f, s1 = 0.f;
#pragma unroll 8
    for (int r = 0; r < 64; r++) {
      const uint32_t pv = *(const uint32_t*)&sy16[r][c0];
      const float rs = srs[r], mu = smu[r];
      s0 += (bf((ushort)(pv & 0xffffu)) - mu) * rs;
      s1 += (bf((ushort)(pv >> 16)) - mu) * rs;
    }
    float* g = G16 + ((size_t)(i * 8 + b) * 16 + slab) * 384 + c0;
    g[0] = s0; g[1] = s1;
  }
}

// ---------------- biattn gate, 384 threads: slab-sum 1 col/thread; gr GEMV
// split 8 lanes/row (48 MACs + 8-lane shuffle reduce); cs GEMV 1 out/thread.
__global__ __launch_bounds__(384) void gate_kernel(const float* __restrict__ G16,
    const float* __restrict__ lng, const float* __restrict__ lnb,
    const float* __restrict__ grw, const float* __restrict__ grb,
    const float* __restrict__ csw, const float* __restrict__ csb, float* __restrict__ cbuf)
{
  const int b = blockIdx.x, i = blockIdx.y;
  const int ib = i * 8 + b;
  const int t = threadIdx.x;
  __shared__ float sG[384];
  __shared__ float g48[48];
  {
    const float* g = G16 + (size_t)ib * 16 * 384 + t;
    float s = 0.f;
#pragma unroll
    for (int k = 0; k < 16; k++) s += g[k * 384];
    sG[t] = s * (1.f / 1024.f) * lng[t] + lnb[t];
  }
  __syncthreads();
  {
    const int row = t >> 3, seg = t & 7;      // 48 rows x 8 segs
    const float* wr = grw + (size_t)row * 384 + seg * 48;
    const float* gr = sG + seg * 48;
    float s = 0.f;
#pragma unroll
    for (int k = 0; k < 48; k++) s += gr[k] * wr[k];
    s += __shfl_xor(s, 1, 64); s += __shfl_xor(s, 2, 64); s += __shfl_xor(s, 4, 64);
    if (seg == 0) {
      s += grb[row];
      g48[row] = 0.5f * s * (1.f + erff(s * 0.70710678118f));
    }
  }
  __syncthreads();
  {
    float s = csb[t];
#pragma unroll
    for (int r = 0; r < 48; r++) s += g48[r] * csw[(size_t)t * 48 + r];
    cbuf[(size_t)ib * 384 + t] = 1.f / (1.f + __expf(-s));
  }
}

// ---------------- local: fused GLU + dwconv(k=8, pad 4,3) + BN partial sums
__global__ __launch_bounds__(192) void gludwbn_kernel(const ushort* __restrict__ hchb,
    const float* __restrict__ dww, const float* __restrict__ dwb,
    float* __restrict__ h2, float* __restrict__ bnsum)
{
  const int c = threadIdx.x;           // 192
  const int lt = blockIdx.x, b = blockIdx.y;   // 16 rows per block
  __shared__ float sv[23][192];
  const int l0 = lt * 16;
#pragma unroll 4
  for (int r = 0; r < 23; r++) {
    const int ls = l0 + r - 4;
    float v = 0.f;
    if (ls >= 0 && ls < 1024) {
      const size_t rr = (size_t)((b << 10) + ls) * 384;
      const float a = bf(hchb[rr + c]);
      const float g = bf(hchb[rr + 192 + c]);
      v = a / (1.f + __expf(-g));
    }
    sv[r][c] = v;
  }
  __syncthreads();
  float wk[8];
#pragma unroll
  for (int k = 0; k < 8; k++) wk[k] = dww[(c << 3) + k];
  const float bias = dwb[c];
  float sacc = 0.f, ssacc = 0.f;
  for (int q = 0; q < 16; q++) {
    float s = bias;
#pragma unroll
    for (int k = 0; k < 8; k++) s += sv[q + k][c] * wk[k];
    h2[(size_t)((b << 10) + l0 + q) * 192 + c] = s;
    sacc += s; ssacc += s * s;
  }
  atomicAdd(&bnsum[c], sacc);
  atomicAdd(&bnsum[192 + c], ssacc);
}

extern "C" void kernel_launch(void* const* d_in, const int* in_sizes, int n_in,
                              void* d_out, int out_size, void* d_ws, size_t ws_size,
                              hipStream_t stream) {
  const float* x    = (const float*)d_in[0];
  const float* ipw  = (const float*)d_in[1];
  const float* alog = (const float*)d_in[2];
  const float* cw   = (const float*)d_in[3];
  const float* cbv  = (const float*)d_in[4];
  const float* xw   = (const float*)d_in[5];
  const float* dtw  = (const float*)d_in[6];
  const float* dtb  = (const float*)d_in[7];
  const float* Dpw  = (const float*)d_in[8];
  const float* opw  = (const float*)d_in[9];
  const float* lng  = (const float*)d_in[10];
  const float* lnb  = (const float*)d_in[11];
  const float* grw  = (const float*)d_in[12];
  const float* grb  = (const float*)d_in[13];
  const float* csw  = (const float*)d_in[14];
  const float* csb  = (const float*)d_in[15];
  const float* pw1w = (const float*)d_in[16];
  const float* pw1b = (const float*)d_in[17];
  const float* dww  = (const float*)d_in[18];
  const float* dwb  = (const float*)d_in[19];
  const float* bng  = (const float*)d_in[20];
  const float* bnb  = (const float*)d_in[21];
  const float* pw2w = (const float*)d_in[22];
  const float* pw2b = (const float*)d_in[23];
  float* out = (float*)d_out;

  char* ws = (char*)d_ws;
  // workspace (bytes); peak ~85.6 MB (proven safe by rounds 7-22); xb region unused
  ushort* xzb   = (ushort*)(ws + 6291456);    // 8192*768 bf16       12582912
  ushort* u     = (ushort*)(ws + 18874368);   // 4*8192*384 bf16     25165824
  float*  dbl   = (float*)(ws + 44040192);    // 4*8192*64 f32        8388608
  ushort* y     = (ushort*)(ws + 52428800);   // 4*8192*384 bf16     25165824
  float*  G16   = (float*)(ws + 83886080);    // 32*16*384 f32         786432
  float*  cbuf  = (float*)(ws + 84672512);    // 32*384 f32             49152
  ushort* xwp   = (ushort*)(ws + 84721664);   // 4*64*384 bf16         196608
  ushort* ipwb  = (ushort*)(ws + 84918272);   // 768*192 bf16          294912
  ushort* opwb  = (ushort*)(ws + 85213184);   // 192*384 bf16          147456
  ushort* pw1wb = (ushort*)(ws + 85360640);   // 384*192 bf16          147456
  ushort* pw2wb = (ushort*)(ws + 85508096);   // 192*192 bf16           73728
  float*  bnsum = (float*)(ws + 85581824);    // 384 f32                 1536
  // local-branch aliases in u region (u dead after scan9)
  ushort* hchb = (ushort*)(ws + 18874368);    // 8192*384 bf16        6291456
  float*  h2   = (float*)(ws + 34603008);     // 8192*192 f32         6291456

  // 1. weight conversions + xproj pad (x no longer staged)
  prep_all<<<dim3(580), 256, 0, stream>>>(ipw, ipwb, opw, opwb,
                                          pw1w, pw1wb, pw2w, pw2wb, xw, xwp);
  // 2. xz = x[:,0:192] @ in_proj_w^T (f32 A converted in staging)
  gemm_xz<<<dim3(128, 12), 256, 0, stream>>>(x, ipwb, xzb);
  // 3+4. fused conv + dbl GEMM (32-row tiles, u-tile kept in LDS)
  convdbl32_kernel<<<dim3(256, 4), 256, 0, stream>>>(xzb, cw, cbv, xwp, u, dbl);
  // 5. scan (u dead after this)
  scan9_kernel<<<dim3(24, 8, 4), 256, 0, stream>>>(u, dbl, xzb, alog, dtw, dtb, Dpw, y);
  // 6-7. biattn stats + gate
  lngm_kernel<<<dim3(16, 8, 4), 256, 0, stream>>>(y, G16);
  gate_kernel<<<dim3(8, 4), 384, 0, stream>>>(G16, lng, lnb, grw, grb, csw, csb, cbuf);
  // 8. dual GEMM with fused accgate (zeroes bnsum):
  //    out_proj (A = sum_i y_i*c_i on the fly) -> out[:,0:192];
  //    pw1 (A = x[:,192:384] f32 converted in staging) -> hchb
  gemm_dualfuse<<<dim3(256, 3), 256, 0, stream>>>(
      y, cbuf, opwb, out, x + 192, pw1wb, pw1b, hchb, bnsum);
  // 9. local branch: GLU+dwconv+BN stats
  gludwbn_kernel<<<dim3(64, 8), 192, 0, stream>>>(hchb, dww, dwb, h2, bnsum);
  // 10. pw2 with fused BN+silu -> out[:, 192:384]
  gemm_pw2<<<dim3(128, 3), 256, 0, stream>>>(h2, bnsum, bng, bnb, pw2wb, pw2b, out);
}